// Round 14
// baseline (340.955 us; speedup 1.0000x reference)
//
#include <hip/hip_runtime.h>
#include <stdint.h>

typedef unsigned short u16;
typedef unsigned int u32;
typedef __attribute__((ext_vector_type(8))) short short8;
typedef __attribute__((ext_vector_type(4))) unsigned short ushort4v;
typedef __attribute__((ext_vector_type(4))) float f32x4;

// ---------------- problem constants ----------------
#define Bsz 2
#define Tn 2048
#define Dm 1024
#define H_ATTN 16
#define HDx 64
#define WINx 128
#define H_SSM 8
#define DIx 2048
#define Nst 16
#define DTRx 64
#define Px 256          // DI / H_SSM
#define TOTx 4416       // 2*DI + DTR + 2*H*N  (Win rows)
#define TOT2 6464       // TOTx + DIx : merged [Win;Wres] output width
#define RESOFF 4416     // residual (Wres) column offset in merged proj row
#define OFFC (2*DIx+DTRx+H_SSM*Nst)   // C-section offset in proj row
#define BT (Bsz*Tn)     // 4096
#define NCH 32          // chunks
#define LCH 64          // chunk length

// ---------------- helpers ----------------
__device__ __forceinline__ float b2f(u16 u){ u32 x = ((u32)u)<<16; float f; __builtin_memcpy(&f,&x,4); return f; }
__device__ __forceinline__ u16 f2b(float f){ u32 x; __builtin_memcpy(&x,&f,4); u32 r = x + 0x7fffu + ((x>>16)&1u); return (u16)(r>>16); }

__device__ __forceinline__ float block_sum256(float v){
  #pragma unroll
  for (int o=32;o;o>>=1) v += __shfl_xor(v,o,64);
  __shared__ float sb[4];
  int wid = threadIdx.x>>6;
  if ((threadIdx.x&63)==0) sb[wid]=v;
  __syncthreads();
  v = sb[0]+sb[1]+sb[2]+sb[3];
  __syncthreads();
  return v;
}

__device__ __forceinline__ void gload_lds16(const void* g, void* l){
  __builtin_amdgcn_global_load_lds((const __attribute__((address_space(1))) void*)g,
                                   (__attribute__((address_space(3))) void*)l, 16, 0, 0);
}

// ---------------- fused fp32 -> bf16 convert (all 7 weights, 1 launch) ----------------
struct CvtArgs { const float* s[7]; u16* d[7]; int n[7]; };
__global__ __launch_bounds__(256) void k_cvt_all(CvtArgs a, int total4){
  int i = blockIdx.x*256 + threadIdx.x;   // in float4 units
  if (i >= total4) return;
  int e = i*4;
  #pragma unroll
  for (int j=0;j<7;j++){
    if (e < a.n[j]){
      float4 v = *(const float4*)(a.s[j]+e);
      u16* d = a.d[j]+e;
      d[0]=f2b(v.x); d[1]=f2b(v.y); d[2]=f2b(v.z); d[3]=f2b(v.w);
      return;
    }
    e -= a.n[j];
  }
}

// ---------------- rms over 1024 (fp32 in -> bf16 out) ----------------
__global__ __launch_bounds__(256) void k_rms1024(const float* __restrict__ src, const float* __restrict__ w,
                                                 u16* __restrict__ dst){
  int row = blockIdx.x, tid = threadIdx.x;
  const float* s = src + (size_t)row*1024;
  float v[4]; float ss=0.f;
  #pragma unroll
  for (int i=0;i<4;i++){ v[i] = s[tid + i*256]; ss += v[i]*v[i]; }
  ss = block_sum256(ss);
  float sc = rsqrtf(ss*(1.0f/1024.0f) + 1e-6f);
  u16* d = dst + (size_t)row*1024;
  #pragma unroll
  for (int i=0;i<4;i++){ int c = tid+i*256; d[c] = f2b(v[i]*sc*w[c]); }
}

#define BKq 64

// ---------------- GEMM 256x256, BK=64, 8-wave, 1-phase/K-tile compiler-scheduled body ----
// Stage ALL 4 halves of tile t+1 at tile top -> vmcnt(8) proves tile t's buffer fully
// landed (8 younger loads outstanding). One acquire barrier, then straight-line
// 24 ds_read_b128 + 64 MFMA (compiler-inserted lgkmcnt), one release barrier.
// 4-row x (gxx/2)-col XCD rectangles (A 2MB resident/XCD). bf16 out, col-guarded.
__global__ __launch_bounds__(512,1)
void k_gemm256(const u16* __restrict__ A, const u16* __restrict__ W,
               u16* __restrict__ C16, int M, int N, int K, int gxx){
  __shared__ u16 lds[2][4][128*64];
  int tid = threadIdx.x, lane = tid&63, wid = tid>>6;
  int bid = blockIdx.x;
  int xcd = bid&7, r = bid>>3;          // r in [0, 2*gxx)
  int halfg = gxx>>1;
  int row0 = (xcd>>1)<<2, col0 = (xcd&1)*halfg;
  int bx = col0 + (r>>2), by = row0 + (r&3);
  int bm = by*256, bn = bx*256;
  int wr = wid>>2, wcn = wid&3;          // wr in {0,1}, wcn in {0..3}
  int fr = lane&15, fq = lane>>4;
  f32x4 acc[2][2][4][2];
  #pragma unroll
  for (int a=0;a<2;a++)
    #pragma unroll
    for (int b=0;b<2;b++)
      #pragma unroll
      for (int c=0;c<4;c++)
        #pragma unroll
        for (int d=0;d<2;d++)
          #pragma unroll
          for (int rr=0;rr<4;rr++) acc[a][b][c][d][rr]=0.f;

  auto stageHalf = [&](int b, int q, int tt){
    int k0 = tt*BKq;
    #pragma unroll
    for (int i=0;i<2;i++){
      int idx = i*512 + tid;             // 0..1023 16B-chunks of this half
      int row = idx>>3, c8 = idx&7;
      const u16* src; int gr;
      if (q < 2){ gr = bm + q*128 + row;     if (gr > M-1) gr = M-1; src = A; }
      else      { gr = bn + (q-2)*128 + row; if (gr > N-1) gr = N-1; src = W; }
      gload_lds16(src + (size_t)gr*K + k0 + ((c8 ^ (row&7)))*8, &lds[b][q][(size_t)idx*8]);
    }
  };
  auto loadA = [&](const u16* aP, short8 (&af)[2][4]){
    #pragma unroll
    for (int kk=0;kk<2;kk++)
      #pragma unroll
      for (int mi=0;mi<4;mi++){
        int row = wr*64 + mi*16 + fr;
        af[kk][mi] = *(const short8*)(aP + row*64 + ((kk*4+fq) ^ (row&7))*8);
      }
  };
  auto loadB = [&](const u16* bP, short8 (&bf)[2][2]){
    #pragma unroll
    for (int kk=0;kk<2;kk++)
      #pragma unroll
      for (int ni=0;ni<2;ni++){
        int row = wcn*32 + ni*16 + fr;
        bf[kk][ni] = *(const short8*)(bP + row*64 + ((kk*4+fq) ^ (row&7))*8);
      }
  };

  int NT = K/BKq;
  // prologue: stage all 4 halves of tile 0 into buf0
  stageHalf(0,0,0); stageHalf(0,1,0); stageHalf(0,2,0); stageHalf(0,3,0);

  for (int t=0;t<NT;t++){
    int cb = t&1, nb = cb^1;
    if (t+1 < NT){
      stageHalf(nb,0,t+1); stageHalf(nb,1,t+1); stageHalf(nb,2,t+1); stageHalf(nb,3,t+1);
      asm volatile("s_waitcnt vmcnt(8)" ::: "memory");   // all of tile t's 8 loads landed
    } else {
      asm volatile("s_waitcnt vmcnt(0)" ::: "memory");
    }
    __builtin_amdgcn_sched_barrier(0);
    __builtin_amdgcn_s_barrier();        // cross-wave visibility of buffer cb
    __builtin_amdgcn_sched_barrier(0);
    {
      const u16* A0 = &lds[cb][0][0];
      const u16* A1 = &lds[cb][1][0];
      const u16* B0 = &lds[cb][2][0];
      const u16* B1 = &lds[cb][3][0];
      short8 af0[2][4], af1[2][4], bf0[2][2], bf1[2][2];
      loadA(A0, af0); loadB(B0, bf0); loadB(B1, bf1); loadA(A1, af1);
      __builtin_amdgcn_s_setprio(1);
      #pragma unroll
      for (int kk=0;kk<2;kk++)
        #pragma unroll
        for (int mi=0;mi<4;mi++)
          #pragma unroll
          for (int ni=0;ni<2;ni++)
            acc[0][0][mi][ni] = __builtin_amdgcn_mfma_f32_16x16x32_bf16(af0[kk][mi], bf0[kk][ni], acc[0][0][mi][ni], 0,0,0);
      #pragma unroll
      for (int kk=0;kk<2;kk++)
        #pragma unroll
        for (int mi=0;mi<4;mi++)
          #pragma unroll
          for (int ni=0;ni<2;ni++)
            acc[0][1][mi][ni] = __builtin_amdgcn_mfma_f32_16x16x32_bf16(af0[kk][mi], bf1[kk][ni], acc[0][1][mi][ni], 0,0,0);
      #pragma unroll
      for (int kk=0;kk<2;kk++)
        #pragma unroll
        for (int mi=0;mi<4;mi++)
          #pragma unroll
          for (int ni=0;ni<2;ni++)
            acc[1][1][mi][ni] = __builtin_amdgcn_mfma_f32_16x16x32_bf16(af1[kk][mi], bf1[kk][ni], acc[1][1][mi][ni], 0,0,0);
      #pragma unroll
      for (int kk=0;kk<2;kk++)
        #pragma unroll
        for (int mi=0;mi<4;mi++)
          #pragma unroll
          for (int ni=0;ni<2;ni++)
            acc[1][0][mi][ni] = __builtin_amdgcn_mfma_f32_16x16x32_bf16(af1[kk][mi], bf0[kk][ni], acc[1][0][mi][ni], 0,0,0);
      __builtin_amdgcn_s_setprio(0);
    }
    __builtin_amdgcn_sched_barrier(0);
    __builtin_amdgcn_s_barrier();        // release: cb fully consumed before next stages
  }
  // epilogue: bf16 C write
  #pragma unroll
  for (int mh=0;mh<2;mh++)
    #pragma unroll
    for (int nh=0;nh<2;nh++)
      #pragma unroll
      for (int mi=0;mi<4;mi++)
        #pragma unroll
        for (int ni=0;ni<2;ni++){
          int row0o = bm + mh*128 + wr*64 + mi*16 + fq*4;
          int col  = bn + nh*128 + wcn*32 + ni*16 + fr;
          if (col < N){
            #pragma unroll
            for (int rr=0;rr<4;rr++)
              C16[(size_t)(row0o+rr)*N + col] = f2b(acc[mh][nh][mi][ni][rr]);
          }
        }
}

// ---------------- GEMM 128xBN, BK=64, depth-2 counted-vmcnt pipeline (r5-proven) ----
// NWC=1: BN=64, 48KB LDS, 3 blk/CU. XCD super-tiling (bx=r>>2, by=super*4+(r&3)).
// mode: 0 C=acc | 2 C16=bf16(acc) | 3 C=ADD+acc
template<int NWC>
__global__ __launch_bounds__(256, (NWC==2?2:3))
void k_gemm(const u16* __restrict__ A, const u16* __restrict__ W,
            float* __restrict__ C, u16* __restrict__ C16, const float* __restrict__ ADD,
            int M, int N, int K, int gx, int mode){
  constexpr int BN    = 64*NWC;
  constexpr int ROWS  = 128 + BN;
  constexpr int NLOADS= ROWS/32;
  constexpr int MFRAG = (NWC==2)?4:2;
  __shared__ u16 lds[2][ROWS*64];
  int tid = threadIdx.x, lane = tid&63, wid = tid>>6;
  int nwg = gridDim.x;
  int cpx = nwg>>3;
  int bid = blockIdx.x;
  int swz = (bid&7)*cpx + (bid>>3);
  int fourgx = gx<<2;
  int super = swz / fourgx;
  int r     = swz % fourgx;
  int bx = r >> 2;
  int by = (super<<2) + (r&3);
  int bm = by*128, bn = bx*BN;
  int wc = (NWC==2) ? (wid&1) : 0;
  int wr = (NWC==2) ? (wid>>1) : wid;
  int fr = lane&15, fq = lane>>4;
  int s7 = fr&7;
  f32x4 acc[MFRAG][4];
  #pragma unroll
  for (int mi=0;mi<MFRAG;mi++)
    #pragma unroll
    for (int ni=0;ni<4;ni++)
      #pragma unroll
      for (int rr=0;rr<4;rr++) acc[mi][ni][rr]=0.f;

  auto stage = [&](int buf, int t){
    int k0 = t*BKq;
    #pragma unroll
    for (int i=0;i<NLOADS;i++){
      int chunk = i*256 + tid;
      int row = chunk>>3, c8 = chunk&7;
      const u16* src;
      if (row < 128){ int ra = bm + row; if (ra > M-1) ra = M-1; src = A + (size_t)ra*K; }
      else          { int rb = bn + row-128; if (rb > N-1) rb = N-1; src = W + (size_t)rb*K; }
      gload_lds16(src + k0 + ((c8 ^ (row&7)))*8, &lds[buf][(size_t)chunk*8]);
    }
  };

  int NT = K/BKq;
  stage(0, 0);
  stage(1, 1);
  for (int t=0;t<NT;t++){
    int cur = t&1;
    if (t+1 < NT){
      if constexpr (NWC==2) asm volatile("s_waitcnt vmcnt(8)" ::: "memory");
      else                  asm volatile("s_waitcnt vmcnt(6)" ::: "memory");
    } else {
      asm volatile("s_waitcnt vmcnt(0)" ::: "memory");
    }
    __builtin_amdgcn_sched_barrier(0);
    __builtin_amdgcn_s_barrier();
    #pragma unroll
    for (int kk=0;kk<2;kk++){
      short8 bf4[4], af4[MFRAG];
      int slotb = ((kk*4 + fq) ^ s7)*8;
      #pragma unroll
      for (int ni=0;ni<4;ni++)
        bf4[ni] = *(const short8*)(&lds[cur][(128 + wc*64 + ni*16 + fr)*64 + slotb]);
      #pragma unroll
      for (int mi=0;mi<MFRAG;mi++)
        af4[mi] = *(const short8*)(&lds[cur][(wr*(MFRAG*16) + mi*16 + fr)*64 + slotb]);
      #pragma unroll
      for (int mi=0;mi<MFRAG;mi++)
        #pragma unroll
        for (int ni=0;ni<4;ni++)
          acc[mi][ni] = __builtin_amdgcn_mfma_f32_16x16x32_bf16(af4[mi], bf4[ni], acc[mi][ni], 0,0,0);
    }
    asm volatile("s_waitcnt lgkmcnt(0)" ::: "memory");
    __builtin_amdgcn_sched_barrier(0);
    __builtin_amdgcn_s_barrier();
    if (t+2 < NT) stage(cur, t+2);
  }
  #pragma unroll
  for (int mi=0;mi<MFRAG;mi++){
    int row0 = bm + wr*(MFRAG*16) + mi*16 + fq*4;
    #pragma unroll
    for (int ni=0;ni<4;ni++){
      int col = bn + wc*64 + ni*16 + fr;
      if (col < N){
        #pragma unroll
        for (int rr=0;rr<4;rr++){
          size_t idx = (size_t)(row0+rr)*N + col;
          float v = acc[mi][ni][rr];
          if (mode == 0)      C[idx] = v;
          else if (mode == 2) C16[idx] = f2b(v);
          else                C[idx] = ADD[idx] + v;
        }
      }
    }
  }
}

// ---------------- dt prep (proj bf16, stride TOT2, vectorized short8 loads) ----------------
__global__ __launch_bounds__(256) void k_dtprep(const u16* __restrict__ proj, const float* __restrict__ Wdt,
      const float* __restrict__ dt_bias, const float* __restrict__ A_log,
      float* __restrict__ dtA, float* __restrict__ dtB){
  int idx = blockIdx.x*256 + threadIdx.x;  // BT*H_SSM
  int h = idx & 7; int bt = idx >> 3;
  const u16* dtl  = proj + (size_t)bt*TOT2 + 2*DIx;
  const float* wrow = Wdt + h*64;
  float v = dt_bias[h];
  #pragma unroll
  for (int i8=0;i8<8;i8++){
    short8 dv = *(const short8*)(dtl + i8*8);
    #pragma unroll
    for (int e=0;e<8;e++) v += b2f((u16)dv[e])*wrow[i8*8+e];
  }
  float sp = (v > 20.0f) ? v : log1pf(expf(v));
  float dt = fminf(fmaxf(sp, 1e-4f), 1.0f);
  const u16* bm = proj + (size_t)bt*TOT2 + 2*DIx + DTRx + h*16;
  short8 b0 = *(const short8*)(bm);
  short8 b1 = *(const short8*)(bm+8);
  #pragma unroll
  for (int n=0;n<16;n++){
    float Av = -expf(A_log[h*16+n]);
    float bv = (n<8) ? b2f((u16)b0[n]) : b2f((u16)b1[n-8]);
    dtA[(size_t)idx*16+n] = dt*Av;
    dtB[(size_t)idx*16+n] = dt*bv;
  }
}

// ---------------- scan phase 1: local scan (conv+silu fused, +residual col), y bf16 ----------------
__global__ __launch_bounds__(256) void k_scan1(const float* __restrict__ dtA, const float* __restrict__ dtB,
    const u16* __restrict__ proj, const float* __restrict__ cw, const float* __restrict__ cb,
    float* __restrict__ expS, u16* __restrict__ y, float* __restrict__ LS){
  __shared__ float sA[1024], sS[1024], sB[1024], sC[1024];
  int bx = blockIdx.x;                 // b*256 + h*32 + c
  int c = bx & 31, h = (bx>>5)&7, b = bx>>8;
  int tid = threadIdx.x;
  size_t t0 = (size_t)b*Tn + c*64;
  int j = tid>>2, n0 = (tid&3)*4;
  {
    size_t ga = (t0 + j)*128 + h*16 + n0;
    float4 va = *(const float4*)(dtA + ga);
    float4 vb = *(const float4*)(dtB + ga);
    ushort4v vc = *(const ushort4v*)(proj + (t0 + j)*TOT2 + OFFC + h*16 + n0);
    *(float4*)(&sA[j*16+n0]) = va;
    *(float4*)(&sB[j*16+n0]) = vb;
    sC[j*16+n0+0] = b2f(vc[0]); sC[j*16+n0+1] = b2f(vc[1]);
    sC[j*16+n0+2] = b2f(vc[2]); sC[j*16+n0+3] = b2f(vc[3]);
  }
  __syncthreads();
  if (tid < 16){
    float cum = 0.f;
    for (int jj=0;jj<64;jj++){ cum += sA[jj*16+tid]; sS[jj*16+tid] = cum; }
  }
  __syncthreads();
  {
    float e[4], s4[4];
    #pragma unroll
    for (int i=0;i<4;i++){ e[i] = expf(sA[j*16+n0+i]); s4[i] = expf(sS[j*16+n0+i]); }
    #pragma unroll
    for (int i=0;i<4;i++){ sA[j*16+n0+i] = e[i]; sS[j*16+n0+i] = s4[i]; }
    float4 ev; ev.x=s4[0]; ev.y=s4[1]; ev.z=s4[2]; ev.w=s4[3];
    *(float4*)(expS + (t0+j)*128 + h*16 + n0) = ev;
  }
  __syncthreads();
  float st[16];
  #pragma unroll
  for (int n=0;n<16;n++) st[n]=0.f;
  int ch = h*Px + tid;                        // xin channel
  const u16* pxin = proj + t0*TOT2 + ch;
  const u16* pres = proj + t0*TOT2 + RESOFF + ch;
  float w0=cw[ch*4+0], w1=cw[ch*4+1], w2=cw[ch*4+2], w3=cw[ch*4+3];
  float bcv = cb[ch];
  float x3=0.f, x2=0.f, x1=0.f;
  if (c > 0){
    x3 = b2f(pxin[-(ptrdiff_t)3*TOT2]);
    x2 = b2f(pxin[-(ptrdiff_t)2*TOT2]);
    x1 = b2f(pxin[-(ptrdiff_t)TOT2]);
  }
  u16* yp = y + t0*DIx + ch;
  for (int jj=0;jj<64;jj++){
    float x0 = b2f(pxin[(size_t)jj*TOT2]);
    float cv = bcv + x3*w0 + x2*w1 + x1*w2 + x0*w3;
    float x = cv / (1.0f + expf(-cv));       // silu(conv)
    x3=x2; x2=x1; x1=x0;
    float acc = b2f(pres[(size_t)jj*TOT2]);  // u1 @ Wres^T residual (merged GEMM column)
    #pragma unroll
    for (int n=0;n<16;n++){ st[n] = st[n]*sA[jj*16+n] + x*sB[jj*16+n]; acc += st[n]*sC[jj*16+n]; }
    yp[(size_t)jj*DIx] = f2b(acc);
  }
  float* ls = LS + ((((size_t)b*8+h)*NCH + c)*Px + tid)*16;
  #pragma unroll
  for (int n=0;n<16;n++) ls[n] = st[n];
}

// ---------------- scan phase 2: chunk-state scan ----------------
__global__ __launch_bounds__(256) void k_scan2(const float* __restrict__ expS, const float* __restrict__ LS,
                                               float* __restrict__ H0){
  int bh = blockIdx.x; int b = bh>>3, h = bh&7;
  int tid = threadIdx.x;
  __shared__ float dl[16];
  float Hs[16];
  #pragma unroll
  for (int n=0;n<16;n++) Hs[n]=0.f;
  for (int c=0;c<NCH;c++){
    if (tid<16) dl[tid] = expS[((size_t)b*Tn + c*64 + 63)*128 + h*16 + tid];
    __syncthreads();
    size_t base = ((((size_t)b*8+h)*NCH + c)*Px + tid)*16;
    #pragma unroll
    for (int n=0;n<16;n++){ H0[base+n] = Hs[n]; Hs[n] = Hs[n]*dl[n] + LS[base+n]; }
    __syncthreads();
  }
}

// ---------------- scan phase 3: fixup + Dskip (stride TOT2), bf16 y RMW ----------------
__global__ __launch_bounds__(256) void k_scan3(const u16* __restrict__ proj, const float* __restrict__ expS,
    const float* __restrict__ H0, const float* __restrict__ cw, const float* __restrict__ cb,
    const float* __restrict__ Dskip, u16* __restrict__ y){
  __shared__ float ce[1024];
  int bx = blockIdx.x; int c = bx&31, h=(bx>>5)&7, b=bx>>8;
  int tid = threadIdx.x;
  size_t t0 = (size_t)b*Tn + c*64;
  int j = tid>>2, n0=(tid&3)*4;
  {
    ushort4v cv = *(const ushort4v*)(proj + (t0+j)*TOT2 + OFFC + h*16 + n0);
    float4 evv = *(const float4*)(expS + (t0+j)*128 + h*16 + n0);
    ce[j*16+n0+0] = b2f(cv[0])*evv.x; ce[j*16+n0+1] = b2f(cv[1])*evv.y;
    ce[j*16+n0+2] = b2f(cv[2])*evv.z; ce[j*16+n0+3] = b2f(cv[3])*evv.w;
  }
  __syncthreads();
  float h0[16];
  size_t base = ((((size_t)b*8+h)*NCH + c)*Px + tid)*16;
  #pragma unroll
  for (int n=0;n<16;n++) h0[n] = H0[base+n];
  int ch = h*Px + tid;
  float dsk = Dskip[ch];
  const u16* pxin = proj + t0*TOT2 + ch;
  float w0=cw[ch*4+0], w1=cw[ch*4+1], w2=cw[ch*4+2], w3=cw[ch*4+3];
  float bcv = cb[ch];
  float x3=0.f, x2=0.f, x1=0.f;
  if (c > 0){
    x3 = b2f(pxin[-(ptrdiff_t)3*TOT2]);
    x2 = b2f(pxin[-(ptrdiff_t)2*TOT2]);
    x1 = b2f(pxin[-(ptrdiff_t)TOT2]);
  }
  u16* yp = y + t0*DIx + ch;
  for (int jj=0;jj<64;jj++){
    float x0 = b2f(pxin[(size_t)jj*TOT2]);
    float cv = bcv + x3*w0 + x2*w1 + x1*w2 + x0*w3;
    float x = cv / (1.0f + expf(-cv));
    x3=x2; x2=x1; x1=x0;
    float f = 0.f;
    #pragma unroll
    for (int n=0;n<16;n++) f += ce[jj*16+n]*h0[n];
    size_t yi = (size_t)jj*DIx;
    yp[yi] = f2b(b2f(yp[yi]) + f + dsk*x);
  }
}

// ---------------- gated rms (y bf16, z bf16, stride TOT2) ----------------
__global__ __launch_bounds__(256) void k_gatedrms(const u16* __restrict__ y, const u16* __restrict__ proj,
     const float* __restrict__ w, u16* __restrict__ yn){
  int row = blockIdx.x, tid = threadIdx.x;
  const u16* yr = y + (size_t)row*DIx;
  const u16* zr = proj + (size_t)row*TOT2 + DIx;
  float v[8]; float ss=0.f;
  #pragma unroll
  for (int i=0;i<8;i++){
    int cidx = tid + i*256;
    float z = b2f(zr[cidx]);
    float g = b2f(yr[cidx]) * (z / (1.0f + expf(-z)));
    v[i]=g; ss += g*g;
  }
  ss = block_sum256(ss);
  float sc = rsqrtf(ss*(1.0f/2048.0f) + 1e-6f);
  u16* d = yn + (size_t)row*DIx;
  #pragma unroll
  for (int i=0;i<8;i++){ int cidx=tid+i*256; d[cidx] = f2b(v[i]*sc*w[cidx]); }
}

// ---------------- h = x + sout; u2 = rms(h)*w (bf16) ----------------
__global__ __launch_bounds__(256) void k_addrms(const float* __restrict__ x, const float* __restrict__ sout,
     const float* __restrict__ w, float* __restrict__ hbuf, u16* __restrict__ u2){
  int row=blockIdx.x, tid=threadIdx.x;
  float v[4]; float ss=0.f;
  #pragma unroll
  for (int i=0;i<4;i++){
    int cidx = tid + i*256;
    size_t idx = (size_t)row*1024 + cidx;
    float hv = x[idx] + sout[idx];
    hbuf[idx]=hv; v[i]=hv; ss+=hv*hv;
  }
  ss = block_sum256(ss);
  float sc = rsqrtf(ss*(1.0f/1024.0f)+1e-6f);
  #pragma unroll
  for (int i=0;i<4;i++){ int cidx=tid+i*256; u2[(size_t)row*1024+cidx] = f2b(v[i]*sc*w[cidx]); }
}

// ---------------- rope + transpose to [B,H,T,HD] (bf16), fused-QKV bf16 input ----------------
__global__ __launch_bounds__(256) void k_rope(const u16* __restrict__ qkvb,
    u16* __restrict__ qr, u16* __restrict__ kr, u16* __restrict__ vr){
  int idx = blockIdx.x*256 + threadIdx.x;  // B*T*D
  int d = idx & 63;
  int h = (idx>>6) & 15;
  int t = (idx>>10) & 2047;
  int b = idx >> 21;
  int col = idx & 1023;
  size_t base = (size_t)(idx>>10)*3072;
  int dh = d & 31;
  float ang = (float)t * exp2f(-(float)dh * (13.287712379549449f/32.0f));  // t * 10000^(-dh/32)
  float cs = cosf(ang), sn = sinf(ang);
  int part = (d<32) ? 32 : -32;
  float q = b2f(qkvb[base + col]),        qp = b2f(qkvb[base + col + part]);
  float k = b2f(qkvb[base + 1024 + col]), kp = b2f(qkvb[base + 1024 + col + part]);
  float vv = b2f(qkvb[base + 2048 + col]);
  float rq = (d<32)? -qp : qp;
  float rk = (d<32)? -kp : kp;
  size_t dst = (((size_t)b*H_ATTN + h)*Tn + t)*64 + d;
  qr[dst] = f2b(q*cs + rq*sn);
  kr[dst] = f2b(k*cs + rk*sn);
  vr[dst] = f2b(vv);
}

// ---------------- MFMA sliding-window attention ----------------
#define QT 64
#define KSPAN 192
__device__ __forceinline__ u32 swz128a(int row, int b){  // tile stride 128B
  return (u32)((row*128 + b) ^ ((((row&7)^((row>>3)&7)))<<4));
}
__device__ __forceinline__ u32 swz384a(int row, int b){  // tile stride 384B
  return (u32)((row*384 + b) ^ ((((row&7)^((row>>3)&7)))<<4));
}

__global__ __launch_bounds__(256) void k_attn_mfma(const u16* __restrict__ qr, const u16* __restrict__ kr,
    const u16* __restrict__ vr, u16* __restrict__ ya){
  __shared__ u16 bufK[KSPAN*64];   // 24576 B ; later P[64][192]
  __shared__ u16 bufV[64*KSPAN];   // 24576 B
  int tid = threadIdx.x, lane = tid&63, wid = tid>>6;
  int fr = lane&15, fq = lane>>4;
  int blk = blockIdx.x;            // bh*32 + qt
  int qt = blk & 31, bh = blk >> 5;
  int t0 = qt*QT;
  size_t rowbase = (size_t)bh*Tn;
  char* cK = (char*)bufK;
  char* cV = (char*)bufV;

  #pragma unroll
  for (int it=0; it<6; ++it){
    int chunk = it*256 + tid;
    int row = chunk>>3, c8 = chunk&7;
    int sg = t0 - 128 + row;
    if (sg >= 0){
      short8 v = *(const short8*)(kr + (rowbase+sg)*64 + c8*8);
      *(short8*)(cK + swz128a(row, c8*16)) = v;
    }
  }
  #pragma unroll
  for (int it=0; it<6; ++it){
    int idx = it*256 + tid;          // 1536 items
    int s = idx>>3, c8 = idx&7, d0 = c8*8;
    int sg = t0 - 128 + s;
    short8 v;
    if (sg >= 0) v = *(const short8*)(vr + (rowbase+sg)*64 + d0);
    else         v = short8{0,0,0,0,0,0,0,0};
    #pragma unroll
    for (int e=0;e<8;e++)
      *(u16*)(cV + swz384a(d0+e, s*2)) = (u16)v[e];
  }
  __syncthreads();

  f32x4 acc[12];
  #pragma unroll
  for (int j=0;j<12;j++)
    #pragma unroll
    for (int r=0;r<4;r++) acc[j][r]=0.f;
  #pragma unroll
  for (int kk=0;kk<2;kk++){
    short8 aq = *(const short8*)(qr + (rowbase + t0 + wid*16 + fr)*64 + kk*32 + fq*8);
    #pragma unroll
    for (int j=0;j<12;j++){
      short8 bk = *(const short8*)(cK + swz128a(j*16+fr, kk*64 + fq*16));
      acc[j] = __builtin_amdgcn_mfma_f32_16x16x32_bf16(aq, bk, acc[j], 0,0,0);
    }
  }

  float p[12][4];
  int cb = lane&15;
  #pragma unroll
  for (int r=0;r<4;r++){
    int rq = wid*16 + (lane>>4)*4 + r;
    float m = -3.0e38f;
    #pragma unroll
    for (int j=0;j<12;j++){
      int c = j*16 + cb;
      bool allowed = (c > rq) && (c <= rq+128) && (c >= 128 - t0);
      float v = allowed ? acc[j][r]*0.125f : -3.0e38f;
      p[j][r] = v;
      m = fmaxf(m, v);
    }
    #pragma unroll
    for (int o=1;o<16;o<<=1) m = fmaxf(m, __shfl_xor(m, o, 64));
    float sum = 0.f;
    #pragma unroll
    for (int j=0;j<12;j++){ float e = __expf(p[j][r]-m); p[j][r]=e; sum += e; }
    #pragma unroll
    for (int o=1;o<16;o<<=1) sum += __shfl_xor(sum, o, 64);
    float inv = 1.0f/sum;
    #pragma unroll
    for (int j=0;j<12;j++) p[j][r] *= inv;
  }
  __syncthreads();

  #pragma unroll
  for (int r=0;r<4;r++){
    int rq = wid*16 + (lane>>4)*4 + r;
    #pragma unroll
    for (int j=0;j<12;j++){
      *(u16*)(cK + swz384a(rq, (j*16+cb)*2)) = f2b(p[j][r]);
    }
  }
  __syncthreads();

  f32x4 acc2[4];
  #pragma unroll
  for (int f=0;f<4;f++)
    #pragma unroll
    for (int r=0;r<4;r++) acc2[f][r]=0.f;
  #pragma unroll
  for (int kk=0;kk<6;kk++){
    short8 ap = *(const short8*)(cK + swz384a(wid*16 + fr, kk*64 + fq*16));
    #pragma unroll
    for (int f=0;f<4;f++){
      short8 bv = *(const short8*)(cV + swz384a(f*16+fr, kk*64 + fq*16));
      acc2[f] = __builtin_amdgcn_mfma_f32_16x16x32_bf16(ap, bv, acc2[f], 0,0,0);
    }
  }
  int b = bh >> 4, h = bh & 15;
  #pragma unroll
  for (int f=0;f<4;f++){
    int d = f*16 + cb;
    #pragma unroll
    for (int r=0;r<4;r++){
      int q = t0 + wid*16 + (lane>>4)*4 + r;
      ya[((size_t)b*Tn + q)*Dm + h*64 + d] = f2b(acc2[f][r]);
    }
  }
}

// =================================================================
extern "C" void kernel_launch(void* const* d_in, const int* in_sizes, int n_in,
                              void* d_out, int out_size, void* d_ws, size_t ws_size,
                              hipStream_t stream) {
  const float* x        = (const float*)d_in[0];
  const float* norm1_w  = (const float*)d_in[1];
  const float* norm2_w  = (const float*)d_in[2];
  const float* Win      = (const float*)d_in[3];
  const float* Wdt      = (const float*)d_in[4];
  const float* conv_w   = (const float*)d_in[5];
  const float* conv_b   = (const float*)d_in[6];
  const float* A_log    = (const float*)d_in[7];
  const float* Dskip    = (const float*)d_in[8];
  const float* dt_bias  = (const float*)d_in[9];
  const float* ssd_norm = (const float*)d_in[10];
  const float* Wout_ssd = (const float*)d_in[11];
  const float* Wres     = (const float*)d_in[12];
  const float* Wq       = (const float*)d_in[13];
  const float* Wk       = (const float*)d_in[14];
  const float* Wv       = (const float*)d_in[15];
  const float* Wo       = (const float*)d_in[16];

  char* ws = (char*)d_ws;
  size_t off = 0;
  auto alloc = [&](size_t bytes){ size_t r = off; off += (bytes + 255) & ~(size_t)255; return r; };

  size_t o_WinB  = alloc((size_t)TOTx*Dm*2);      // contiguous with WresB: merged [6464,1024]
  size_t o_WresB = alloc((size_t)DIx*Dm*2);
  size_t o_WoutB = alloc((size_t)Dm*DIx*2);
  size_t o_WqB   = alloc((size_t)Dm*Dm*2);
  size_t o_WkB   = alloc((size_t)Dm*Dm*2);
  size_t o_WvB   = alloc((size_t)Dm*Dm*2);
  size_t o_WoB   = alloc((size_t)Dm*Dm*2);
  size_t o_u1    = alloc((size_t)BT*Dm*2);        // later reused as vr
  size_t o_proj  = alloc((size_t)BT*TOT2*2);      // merged bf16 proj (53MB); later qkvb
  size_t o_sout  = alloc((size_t)BT*Dm*4);
  size_t o_dtA   = alloc((size_t)BT*H_SSM*Nst*4);
  size_t o_dtB   = alloc((size_t)BT*H_SSM*Nst*4);
  size_t o_expS  = alloc((size_t)BT*H_SSM*Nst*4);
  size_t o_LS    = alloc((size_t)Bsz*H_SSM*NCH*Px*Nst*4);
  size_t o_H0    = alloc((size_t)Bsz*H_SSM*NCH*Px*Nst*4);
  size_t o_y     = alloc((size_t)BT*DIx*2);       // ybuf16; later yatt
  size_t o_yn    = alloc((size_t)BT*DIx*2);       // yn; later u2
  size_t o_hb    = alloc((size_t)BT*Dm*4);
  size_t o_qr    = alloc((size_t)Bsz*H_ATTN*Tn*HDx*2);
  size_t o_kr    = alloc((size_t)Bsz*H_ATTN*Tn*HDx*2);

  u16* WinB  = (u16*)(ws + o_WinB);    // head of merged [Win;Wres] weight
  u16* WoutB = (u16*)(ws + o_WoutB);
  u16* WqB   = (u16*)(ws + o_WqB);
  u16* u1    = (u16*)(ws + o_u1);
  u16* projb = (u16*)(ws + o_proj);
  float* dtA  = (float*)(ws + o_dtA);
  float* dtB  = (float*)(ws + o_dtB);
  float* expS = (float*)(ws + o_expS);
  float* LS   = (float*)(ws + o_LS);
  float* H0   = (float*)(ws + o_H0);
  u16*   ybuf16 = (u16*)(ws + o_y);
  u16*   yn   = (u16*)(ws + o_yn);
  float* hb   = (float*)(ws + o_hb);
  float* sout = (float*)(ws + o_sout);
  // aliases (lifetimes disjoint)
  u16* qkvb = (u16*)(ws + o_proj);   // proj dead after gatedrms
  u16* qr = (u16*)(ws + o_qr);
  u16* kr = (u16*)(ws + o_kr);
  u16* vr = u1;                      // u1 dead after merged in-proj gemm
  u16* yatt = (u16*)(ws + o_y);      // ybuf16 dead after gatedrms

  // fused weight convert
  {
    CvtArgs a;
    a.s[0]=Win;  a.d[0]=WinB;  a.n[0]=TOTx*Dm;
    a.s[1]=Wres; a.d[1]=(u16*)(ws + o_WresB); a.n[1]=DIx*Dm;
    a.s[2]=Wout_ssd; a.d[2]=WoutB; a.n[2]=Dm*DIx;
    a.s[3]=Wq; a.d[3]=WqB; a.n[3]=Dm*Dm;
    a.s[4]=Wk; a.d[4]=(u16*)(ws + o_WkB); a.n[4]=Dm*Dm;
    a.s[5]=Wv; a.d[5]=(u16*)(ws + o_WvB); a.n[5]=Dm*Dm;
    a.s[6]=Wo; a.d[6]=(u16*)(ws + o_WoB); a.n[6]=Dm*Dm;
    int total4 = (a.n[0]+a.n[1]+a.n[2]+a.n[3]+a.n[4]+a.n[5]+a.n[6])/4;
    k_cvt_all<<<dim3((total4+255)/256), dim3(256), 0, stream>>>(a, total4);
  }

  // 1) u1 = rms(x, norm1_w)
  k_rms1024<<<dim3(BT), dim3(256), 0, stream>>>(x, norm1_w, u1);
  // 2) projb = bf16(u1 @ [Win;Wres]^T)  256^2 1-phase/K-tile: gxx=26, 416 blocks
  k_gemm256<<<dim3(16*26), dim3(512), 0, stream>>>(u1, WinB, projb, BT, TOT2, Dm, 26);
  // 3) dt prep
  k_dtprep<<<dim3(BT*H_SSM/256), dim3(256), 0, stream>>>(projb, Wdt, dt_bias, A_log, dtA, dtB);
  // 4) chunked scan (conv+silu fused; scan1 folds residual column; y bf16)
  k_scan1<<<dim3(Bsz*H_SSM*NCH), dim3(256), 0, stream>>>(dtA, dtB, projb, conv_w, conv_b, expS, ybuf16, LS);
  k_scan2<<<dim3(Bsz*H_SSM), dim3(256), 0, stream>>>(expS, LS, H0);
  k_scan3<<<dim3(Bsz*H_SSM*NCH), dim3(256), 0, stream>>>(projb, expS, H0, conv_w, conv_b, Dskip, ybuf16);
  // 5) yn = rms(y * silu(z)) * ssd_norm_w
  k_gatedrms<<<dim3(BT), dim3(256), 0, stream>>>(ybuf16, projb, ssd_norm, yn);
  // 6) sout = yn @ Wout^T  BN=64: gx=16, 512 blocks, K=2048
  k_gemm<1><<<dim3(16*32), dim3(256), 0, stream>>>(yn, WoutB, sout, nullptr, nullptr, BT, Dm, DIx, 16, 0);
  // 7) h = x + sout; u2 = rms(h)*norm2_w
  k_addrms<<<dim3(BT), dim3(256), 0, stream>>>(x, sout, norm2_w, hb, (u16*)(ws + o_yn));
  u16* u2p = (u16*)(ws + o_yn);
  // 8) fused QKV projection, bf16 out  BN=64: gx=48, 1536 blocks @3/CU = 2 rounds
  k_gemm<1><<<dim3(48*32), dim3(256), 0, stream>>>(u2p, WqB, nullptr, qkvb, nullptr, BT, 3*Dm, Dm, 48, 2);
  // 9) rope + transpose (bf16 in)
  k_rope<<<dim3(BT*Dm/256), dim3(256), 0, stream>>>(qkvb, qr, kr, vr);
  // 10) attention (MFMA sliding-window)
  k_attn_mfma<<<dim3(Bsz*H_ATTN*(Tn/QT)), dim3(256), 0, stream>>>(qr, kr, vr, yatt);
  // 11) out = hb + yatt @ Wo^T  BN=64: gx=16, 512 blocks
  k_gemm<1><<<dim3(16*32), dim3(256), 0, stream>>>(yatt, (u16*)(ws + o_WoB), (float*)d_out, nullptr, hb, BT, Dm, Dm, 16, 3);
  (void)in_sizes; (void)n_in; (void)out_size; (void)ws_size;
}

// Round 15
// 320.956 us; speedup vs baseline: 1.0623x; 1.0623x over previous
//
#include <hip/hip_runtime.h>
#include <stdint.h>

typedef unsigned short u16;
typedef unsigned int u32;
typedef __attribute__((ext_vector_type(8))) short short8;
typedef __attribute__((ext_vector_type(4))) unsigned short ushort4v;
typedef __attribute__((ext_vector_type(4))) float f32x4;

// ---------------- problem constants ----------------
#define Bsz 2
#define Tn 2048
#define Dm 1024
#define H_ATTN 16
#define HDx 64
#define WINx 128
#define H_SSM 8
#define DIx 2048
#define Nst 16
#define DTRx 64
#define Px 256          // DI / H_SSM
#define TOTx 4416       // 2*DI + DTR + 2*H*N  (Win rows)
#define TOT2 6464       // TOTx + DIx : merged [Win;Wres] output width
#define RESOFF 4416     // residual (Wres) column offset in merged proj row
#define OFFC (2*DIx+DTRx+H_SSM*Nst)   // C-section offset in proj row
#define BT (Bsz*Tn)     // 4096
#define NCH 32          // chunks
#define LCH 64          // chunk length

// ---------------- helpers ----------------
__device__ __forceinline__ float b2f(u16 u){ u32 x = ((u32)u)<<16; float f; __builtin_memcpy(&f,&x,4); return f; }
__device__ __forceinline__ u16 f2b(float f){ u32 x; __builtin_memcpy(&x,&f,4); u32 r = x + 0x7fffu + ((x>>16)&1u); return (u16)(r>>16); }

__device__ __forceinline__ float block_sum256(float v){
  #pragma unroll
  for (int o=32;o;o>>=1) v += __shfl_xor(v,o,64);
  __shared__ float sb[4];
  int wid = threadIdx.x>>6;
  if ((threadIdx.x&63)==0) sb[wid]=v;
  __syncthreads();
  v = sb[0]+sb[1]+sb[2]+sb[3];
  __syncthreads();
  return v;
}

__device__ __forceinline__ void gload_lds16(const void* g, void* l){
  __builtin_amdgcn_global_load_lds((const __attribute__((address_space(1))) void*)g,
                                   (__attribute__((address_space(3))) void*)l, 16, 0, 0);
}

// ---------------- fused fp32 -> bf16 convert (all 7 weights, 1 launch) ----------------
struct CvtArgs { const float* s[7]; u16* d[7]; int n[7]; };
__global__ __launch_bounds__(256) void k_cvt_all(CvtArgs a, int total4){
  int i = blockIdx.x*256 + threadIdx.x;   // in float4 units
  if (i >= total4) return;
  int e = i*4;
  #pragma unroll
  for (int j=0;j<7;j++){
    if (e < a.n[j]){
      float4 v = *(const float4*)(a.s[j]+e);
      u16* d = a.d[j]+e;
      d[0]=f2b(v.x); d[1]=f2b(v.y); d[2]=f2b(v.z); d[3]=f2b(v.w);
      return;
    }
    e -= a.n[j];
  }
}

// ---------------- rms over 1024 (fp32 in -> bf16 out) ----------------
__global__ __launch_bounds__(256) void k_rms1024(const float* __restrict__ src, const float* __restrict__ w,
                                                 u16* __restrict__ dst){
  int row = blockIdx.x, tid = threadIdx.x;
  const float* s = src + (size_t)row*1024;
  float v[4]; float ss=0.f;
  #pragma unroll
  for (int i=0;i<4;i++){ v[i] = s[tid + i*256]; ss += v[i]*v[i]; }
  ss = block_sum256(ss);
  float sc = rsqrtf(ss*(1.0f/1024.0f) + 1e-6f);
  u16* d = dst + (size_t)row*1024;
  #pragma unroll
  for (int i=0;i<4;i++){ int c = tid+i*256; d[c] = f2b(v[i]*sc*w[c]); }
}

#define BKq 64

// ---------------- GEMM 256x256, BK=64, 8-wave 4-phase/K-tile (r13-best: reg-cached) ----
// Stage slot order {A0,B0,B1,A1}; uniform vmcnt(6)/phase; two barriers/phase.
// Register-cached fragments: A loaded p0/p2, B0 p0 (reused p3), B1 p1 (reused p2).
// 4-row x (gxx/2)-col XCD rectangles (A 2MB resident/XCD). bf16 out, col-guarded.
__global__ __launch_bounds__(512,1)
void k_gemm256(const u16* __restrict__ A, const u16* __restrict__ W,
               u16* __restrict__ C16, int M, int N, int K, int gxx){
  __shared__ u16 lds[2][4][128*64];
  int tid = threadIdx.x, lane = tid&63, wid = tid>>6;
  int bid = blockIdx.x;
  int xcd = bid&7, r = bid>>3;          // r in [0, 2*gxx)
  int halfg = gxx>>1;
  int row0 = (xcd>>1)<<2, col0 = (xcd&1)*halfg;
  int bx = col0 + (r>>2), by = row0 + (r&3);
  int bm = by*256, bn = bx*256;
  int wr = wid>>2, wcn = wid&3;          // wr in {0,1}, wcn in {0..3}
  int fr = lane&15, fq = lane>>4;
  f32x4 acc[2][2][4][2];
  #pragma unroll
  for (int a=0;a<2;a++)
    #pragma unroll
    for (int b=0;b<2;b++)
      #pragma unroll
      for (int c=0;c<4;c++)
        #pragma unroll
        for (int d=0;d<2;d++)
          #pragma unroll
          for (int rr=0;rr<4;rr++) acc[a][b][c][d][rr]=0.f;

  auto stageHalf = [&](int b, int q, int tt){
    int k0 = tt*BKq;
    #pragma unroll
    for (int i=0;i<2;i++){
      int idx = i*512 + tid;             // 0..1023 16B-chunks of this half
      int row = idx>>3, c8 = idx&7;
      const u16* src; int gr;
      if (q < 2){ gr = bm + q*128 + row;     if (gr > M-1) gr = M-1; src = A; }
      else      { gr = bn + (q-2)*128 + row; if (gr > N-1) gr = N-1; src = W; }
      gload_lds16(src + (size_t)gr*K + k0 + ((c8 ^ (row&7)))*8, &lds[b][q][(size_t)idx*8]);
    }
  };
  auto loadA = [&](const u16* aP, short8 (&af)[2][4]){
    #pragma unroll
    for (int kk=0;kk<2;kk++)
      #pragma unroll
      for (int mi=0;mi<4;mi++){
        int row = wr*64 + mi*16 + fr;
        af[kk][mi] = *(const short8*)(aP + row*64 + ((kk*4+fq) ^ (row&7))*8);
      }
  };
  auto loadB = [&](const u16* bP, short8 (&bf)[2][2]){
    #pragma unroll
    for (int kk=0;kk<2;kk++)
      #pragma unroll
      for (int ni=0;ni<2;ni++){
        int row = wcn*32 + ni*16 + fr;
        bf[kk][ni] = *(const short8*)(bP + row*64 + ((kk*4+fq) ^ (row&7))*8);
      }
  };

  int NT = K/BKq;
  stageHalf(0,0,0); stageHalf(0,2,0); stageHalf(0,3,0); stageHalf(0,1,0);

  short8 af[2][4], bf0[2][2], bf1[2][2];
  for (int t=0;t<NT;t++){
    int cb = t&1, nb = cb^1;
    int tn = (t+1 < NT) ? t+1 : t;       // clamped re-stage on last tile (unused)
    const u16* A0 = &lds[cb][0][0];
    const u16* A1 = &lds[cb][1][0];
    const u16* B0 = &lds[cb][2][0];
    const u16* B1 = &lds[cb][3][0];
    // ---- phase 0: compute (A0,B0); load af<-A0, bf0<-B0
    stageHalf(nb,0,tn);
    asm volatile("s_waitcnt vmcnt(6)" ::: "memory");
    __builtin_amdgcn_sched_barrier(0);
    __builtin_amdgcn_s_barrier();
    loadA(A0, af); loadB(B0, bf0);
    asm volatile("s_waitcnt lgkmcnt(0)" ::: "memory");
    __builtin_amdgcn_sched_barrier(0);
    __builtin_amdgcn_s_setprio(1);
    #pragma unroll
    for (int kk=0;kk<2;kk++)
      #pragma unroll
      for (int mi=0;mi<4;mi++)
        #pragma unroll
        for (int ni=0;ni<2;ni++)
          acc[0][0][mi][ni] = __builtin_amdgcn_mfma_f32_16x16x32_bf16(af[kk][mi], bf0[kk][ni], acc[0][0][mi][ni], 0,0,0);
    __builtin_amdgcn_s_setprio(0);
    __builtin_amdgcn_s_barrier();
    // ---- phase 1: compute (A0,B1); load bf1<-B1 (af reused)
    stageHalf(nb,2,tn);
    asm volatile("s_waitcnt vmcnt(6)" ::: "memory");
    __builtin_amdgcn_sched_barrier(0);
    __builtin_amdgcn_s_barrier();
    loadB(B1, bf1);
    asm volatile("s_waitcnt lgkmcnt(0)" ::: "memory");
    __builtin_amdgcn_sched_barrier(0);
    __builtin_amdgcn_s_setprio(1);
    #pragma unroll
    for (int kk=0;kk<2;kk++)
      #pragma unroll
      for (int mi=0;mi<4;mi++)
        #pragma unroll
        for (int ni=0;ni<2;ni++)
          acc[0][1][mi][ni] = __builtin_amdgcn_mfma_f32_16x16x32_bf16(af[kk][mi], bf1[kk][ni], acc[0][1][mi][ni], 0,0,0);
    __builtin_amdgcn_s_setprio(0);
    __builtin_amdgcn_s_barrier();
    // ---- phase 2: compute (A1,B1); load af<-A1 (bf1 reused)
    stageHalf(nb,3,tn);
    asm volatile("s_waitcnt vmcnt(6)" ::: "memory");
    __builtin_amdgcn_sched_barrier(0);
    __builtin_amdgcn_s_barrier();
    loadA(A1, af);
    asm volatile("s_waitcnt lgkmcnt(0)" ::: "memory");
    __builtin_amdgcn_sched_barrier(0);
    __builtin_amdgcn_s_setprio(1);
    #pragma unroll
    for (int kk=0;kk<2;kk++)
      #pragma unroll
      for (int mi=0;mi<4;mi++)
        #pragma unroll
        for (int ni=0;ni<2;ni++)
          acc[1][1][mi][ni] = __builtin_amdgcn_mfma_f32_16x16x32_bf16(af[kk][mi], bf1[kk][ni], acc[1][1][mi][ni], 0,0,0);
    __builtin_amdgcn_s_setprio(0);
    __builtin_amdgcn_s_barrier();
    // ---- phase 3: compute (A1,B0); pure register phase (af, bf0 reused)
    stageHalf(nb,1,tn);
    asm volatile("s_waitcnt vmcnt(6)" ::: "memory");
    __builtin_amdgcn_sched_barrier(0);
    __builtin_amdgcn_s_barrier();
    __builtin_amdgcn_s_setprio(1);
    #pragma unroll
    for (int kk=0;kk<2;kk++)
      #pragma unroll
      for (int mi=0;mi<4;mi++)
        #pragma unroll
        for (int ni=0;ni<2;ni++)
          acc[1][0][mi][ni] = __builtin_amdgcn_mfma_f32_16x16x32_bf16(af[kk][mi], bf0[kk][ni], acc[1][0][mi][ni], 0,0,0);
    __builtin_amdgcn_s_setprio(0);
    __builtin_amdgcn_s_barrier();
  }
  // epilogue: bf16 C write
  #pragma unroll
  for (int mh=0;mh<2;mh++)
    #pragma unroll
    for (int nh=0;nh<2;nh++)
      #pragma unroll
      for (int mi=0;mi<4;mi++)
        #pragma unroll
        for (int ni=0;ni<2;ni++){
          int row0o = bm + mh*128 + wr*64 + mi*16 + fq*4;
          int col  = bn + nh*128 + wcn*32 + ni*16 + fr;
          if (col < N){
            #pragma unroll
            for (int rr=0;rr<4;rr++)
              C16[(size_t)(row0o+rr)*N + col] = f2b(acc[mh][nh][mi][ni][rr]);
          }
        }
}

// ---------------- GEMM 128xBN, BK=64, depth-2 counted-vmcnt pipeline (r5-proven) ----
// NWC=1: BN=64, 48KB LDS, 3 blk/CU. XCD super-tiling (bx=r>>2, by=super*4+(r&3)).
// mode: 0 C=acc | 2 C16=bf16(acc) | 3 C=ADD+acc | 5 fused-QKV+RoPE transposed write
template<int NWC>
__global__ __launch_bounds__(256, (NWC==2?2:3))
void k_gemm(const u16* __restrict__ A, const u16* __restrict__ W,
            float* __restrict__ C, u16* __restrict__ C16, const float* __restrict__ ADD,
            u16* __restrict__ qro, u16* __restrict__ kro, u16* __restrict__ vro,
            int M, int N, int K, int gx, int mode){
  constexpr int BN    = 64*NWC;
  constexpr int ROWS  = 128 + BN;
  constexpr int NLOADS= ROWS/32;
  constexpr int MFRAG = (NWC==2)?4:2;
  __shared__ u16 lds[2][ROWS*64];
  int tid = threadIdx.x, lane = tid&63, wid = tid>>6;
  int nwg = gridDim.x;
  int cpx = nwg>>3;
  int bid = blockIdx.x;
  int swz = (bid&7)*cpx + (bid>>3);
  int fourgx = gx<<2;
  int super = swz / fourgx;
  int r     = swz % fourgx;
  int bx = r >> 2;
  int by = (super<<2) + (r&3);
  int bm = by*128, bn = bx*BN;
  int wc = (NWC==2) ? (wid&1) : 0;
  int wr = (NWC==2) ? (wid>>1) : wid;
  int fr = lane&15, fq = lane>>4;
  int s7 = fr&7;
  f32x4 acc[MFRAG][4];
  #pragma unroll
  for (int mi=0;mi<MFRAG;mi++)
    #pragma unroll
    for (int ni=0;ni<4;ni++)
      #pragma unroll
      for (int rr=0;rr<4;rr++) acc[mi][ni][rr]=0.f;

  auto stage = [&](int buf, int t){
    int k0 = t*BKq;
    #pragma unroll
    for (int i=0;i<NLOADS;i++){
      int chunk = i*256 + tid;
      int row = chunk>>3, c8 = chunk&7;
      const u16* src;
      if (row < 128){ int ra = bm + row; if (ra > M-1) ra = M-1; src = A + (size_t)ra*K; }
      else          { int rb = bn + row-128; if (rb > N-1) rb = N-1; src = W + (size_t)rb*K; }
      gload_lds16(src + k0 + ((c8 ^ (row&7)))*8, &lds[buf][(size_t)chunk*8]);
    }
  };

  int NT = K/BKq;
  stage(0, 0);
  stage(1, 1);
  for (int t=0;t<NT;t++){
    int cur = t&1;
    if (t+1 < NT){
      if constexpr (NWC==2) asm volatile("s_waitcnt vmcnt(8)" ::: "memory");
      else                  asm volatile("s_waitcnt vmcnt(6)" ::: "memory");
    } else {
      asm volatile("s_waitcnt vmcnt(0)" ::: "memory");
    }
    __builtin_amdgcn_sched_barrier(0);
    __builtin_amdgcn_s_barrier();
    #pragma unroll
    for (int kk=0;kk<2;kk++){
      short8 bf4[4], af4[MFRAG];
      int slotb = ((kk*4 + fq) ^ s7)*8;
      #pragma unroll
      for (int ni=0;ni<4;ni++)
        bf4[ni] = *(const short8*)(&lds[cur][(128 + wc*64 + ni*16 + fr)*64 + slotb]);
      #pragma unroll
      for (int mi=0;mi<MFRAG;mi++)
        af4[mi] = *(const short8*)(&lds[cur][(wr*(MFRAG*16) + mi*16 + fr)*64 + slotb]);
      #pragma unroll
      for (int mi=0;mi<MFRAG;mi++)
        #pragma unroll
        for (int ni=0;ni<4;ni++)
          acc[mi][ni] = __builtin_amdgcn_mfma_f32_16x16x32_bf16(af4[mi], bf4[ni], acc[mi][ni], 0,0,0);
    }
    asm volatile("s_waitcnt lgkmcnt(0)" ::: "memory");
    __builtin_amdgcn_sched_barrier(0);
    __builtin_amdgcn_s_barrier();
    if (t+2 < NT) stage(cur, t+2);
  }
  if (mode == 5){
    // fused QKV + RoPE epilogue: each 64-col tile = one head of one section.
    // Pair (d, d+32) lives in (ni, ni+2) of the SAME thread.
    int sec = bn >> 10;                  // 0=Q, 1=K, 2=V
    int hh  = (bn >> 6) & 15;
    #pragma unroll
    for (int mi=0;mi<MFRAG;mi++){
      #pragma unroll
      for (int rr=0;rr<4;rr++){
        int row = bm + wr*(MFRAG*16) + mi*16 + fq*4 + rr;
        int tt = row & (Tn-1), bb = row >> 11;
        size_t dstb = (((size_t)bb*H_ATTN + hh)*Tn + tt)*64;
        if (sec == 2){
          #pragma unroll
          for (int ni=0;ni<4;ni++)
            vro[dstb + ni*16 + fr] = f2b(acc[mi][ni][rr]);
        } else {
          u16* dst = (sec==0) ? qro : kro;
          #pragma unroll
          for (int ni=0;ni<2;ni++){
            int dh = ni*16 + fr;
            float ang = (float)tt * exp2f(-(float)dh * (13.287712379549449f/32.0f));
            float cs = cosf(ang), sn = sinf(ang);
            float lo = acc[mi][ni][rr], hi = acc[mi][ni+2][rr];
            dst[dstb + dh]      = f2b(lo*cs - hi*sn);
            dst[dstb + dh + 32] = f2b(hi*cs + lo*sn);
          }
        }
      }
    }
    return;
  }
  #pragma unroll
  for (int mi=0;mi<MFRAG;mi++){
    int row0 = bm + wr*(MFRAG*16) + mi*16 + fq*4;
    #pragma unroll
    for (int ni=0;ni<4;ni++){
      int col = bn + wc*64 + ni*16 + fr;
      if (col < N){
        #pragma unroll
        for (int rr=0;rr<4;rr++){
          size_t idx = (size_t)(row0+rr)*N + col;
          float v = acc[mi][ni][rr];
          if (mode == 0)      C[idx] = v;
          else if (mode == 2) C16[idx] = f2b(v);
          else                C[idx] = ADD[idx] + v;
        }
      }
    }
  }
}

// ---------------- dt prep (proj bf16, stride TOT2, vectorized short8 loads) ----------------
__global__ __launch_bounds__(256) void k_dtprep(const u16* __restrict__ proj, const float* __restrict__ Wdt,
      const float* __restrict__ dt_bias, const float* __restrict__ A_log,
      float* __restrict__ dtA, float* __restrict__ dtB){
  int idx = blockIdx.x*256 + threadIdx.x;  // BT*H_SSM
  int h = idx & 7; int bt = idx >> 3;
  const u16* dtl  = proj + (size_t)bt*TOT2 + 2*DIx;
  const float* wrow = Wdt + h*64;
  float v = dt_bias[h];
  #pragma unroll
  for (int i8=0;i8<8;i8++){
    short8 dv = *(const short8*)(dtl + i8*8);
    #pragma unroll
    for (int e=0;e<8;e++) v += b2f((u16)dv[e])*wrow[i8*8+e];
  }
  float sp = (v > 20.0f) ? v : log1pf(expf(v));
  float dt = fminf(fmaxf(sp, 1e-4f), 1.0f);
  const u16* bm = proj + (size_t)bt*TOT2 + 2*DIx + DTRx + h*16;
  short8 b0 = *(const short8*)(bm);
  short8 b1 = *(const short8*)(bm+8);
  #pragma unroll
  for (int n=0;n<16;n++){
    float Av = -expf(A_log[h*16+n]);
    float bv = (n<8) ? b2f((u16)b0[n]) : b2f((u16)b1[n-8]);
    dtA[(size_t)idx*16+n] = dt*Av;
    dtB[(size_t)idx*16+n] = dt*bv;
  }
}

// ---------------- scan phase 1: local scan (conv+silu fused, +residual col), y bf16 ----------------
__global__ __launch_bounds__(256) void k_scan1(const float* __restrict__ dtA, const float* __restrict__ dtB,
    const u16* __restrict__ proj, const float* __restrict__ cw, const float* __restrict__ cb,
    float* __restrict__ expS, u16* __restrict__ y, float* __restrict__ LS){
  __shared__ float sA[1024], sS[1024], sB[1024], sC[1024];
  int bx = blockIdx.x;                 // b*256 + h*32 + c
  int c = bx & 31, h = (bx>>5)&7, b = bx>>8;
  int tid = threadIdx.x;
  size_t t0 = (size_t)b*Tn + c*64;
  int j = tid>>2, n0 = (tid&3)*4;
  {
    size_t ga = (t0 + j)*128 + h*16 + n0;
    float4 va = *(const float4*)(dtA + ga);
    float4 vb = *(const float4*)(dtB + ga);
    ushort4v vc = *(const ushort4v*)(proj + (t0 + j)*TOT2 + OFFC + h*16 + n0);
    *(float4*)(&sA[j*16+n0]) = va;
    *(float4*)(&sB[j*16+n0]) = vb;
    sC[j*16+n0+0] = b2f(vc[0]); sC[j*16+n0+1] = b2f(vc[1]);
    sC[j*16+n0+2] = b2f(vc[2]); sC[j*16+n0+3] = b2f(vc[3]);
  }
  __syncthreads();
  if (tid < 16){
    float cum = 0.f;
    for (int jj=0;jj<64;jj++){ cum += sA[jj*16+tid]; sS[jj*16+tid] = cum; }
  }
  __syncthreads();
  {
    float e[4], s4[4];
    #pragma unroll
    for (int i=0;i<4;i++){ e[i] = expf(sA[j*16+n0+i]); s4[i] = expf(sS[j*16+n0+i]); }
    #pragma unroll
    for (int i=0;i<4;i++){ sA[j*16+n0+i] = e[i]; sS[j*16+n0+i] = s4[i]; }
    float4 ev; ev.x=s4[0]; ev.y=s4[1]; ev.z=s4[2]; ev.w=s4[3];
    *(float4*)(expS + (t0+j)*128 + h*16 + n0) = ev;
  }
  __syncthreads();
  float st[16];
  #pragma unroll
  for (int n=0;n<16;n++) st[n]=0.f;
  int ch = h*Px + tid;                        // xin channel
  const u16* pxin = proj + t0*TOT2 + ch;
  const u16* pres = proj + t0*TOT2 + RESOFF + ch;
  float w0=cw[ch*4+0], w1=cw[ch*4+1], w2=cw[ch*4+2], w3=cw[ch*4+3];
  float bcv = cb[ch];
  float x3=0.f, x2=0.f, x1=0.f;
  if (c > 0){
    x3 = b2f(pxin[-(ptrdiff_t)3*TOT2]);
    x2 = b2f(pxin[-(ptrdiff_t)2*TOT2]);
    x1 = b2f(pxin[-(ptrdiff_t)TOT2]);
  }
  u16* yp = y + t0*DIx + ch;
  for (int jj=0;jj<64;jj++){
    float x0 = b2f(pxin[(size_t)jj*TOT2]);
    float cv = bcv + x3*w0 + x2*w1 + x1*w2 + x0*w3;
    float x = cv / (1.0f + expf(-cv));       // silu(conv)
    x3=x2; x2=x1; x1=x0;
    float acc = b2f(pres[(size_t)jj*TOT2]);  // u1 @ Wres^T residual (merged GEMM column)
    #pragma unroll
    for (int n=0;n<16;n++){ st[n] = st[n]*sA[jj*16+n] + x*sB[jj*16+n]; acc += st[n]*sC[jj*16+n]; }
    yp[(size_t)jj*DIx] = f2b(acc);
  }
  float* ls = LS + ((((size_t)b*8+h)*NCH + c)*Px + tid)*16;
  #pragma unroll
  for (int n=0;n<16;n++) ls[n] = st[n];
}

// ---------------- scan phase 2: chunk-state scan, parallel over (ch,n) ----------------
// grid = Bsz*H_SSM*16 blocks; thread = (16 channels x 16 n); serial over 32 chunks; no barriers.
__global__ __launch_bounds__(256) void k_scan2(const float* __restrict__ expS, const float* __restrict__ LS,
                                               float* __restrict__ H0){
  int blk = blockIdx.x;
  int slice = blk & 15;              // 16-channel slice
  int bh = blk >> 4; int b = bh>>3, h = bh&7;
  int tid = threadIdx.x;
  int ch = slice*16 + (tid>>4);
  int n  = tid & 15;
  float Hs = 0.f;
  for (int c=0;c<NCH;c++){
    float dl = expS[((size_t)b*Tn + c*64 + 63)*128 + h*16 + n];
    size_t base = ((((size_t)b*8+h)*NCH + c)*Px + ch)*16 + n;
    H0[base] = Hs;
    Hs = Hs*dl + LS[base];
  }
}

// ---------------- scan phase 3: fixup + Dskip (stride TOT2), bf16 y RMW ----------------
__global__ __launch_bounds__(256) void k_scan3(const u16* __restrict__ proj, const float* __restrict__ expS,
    const float* __restrict__ H0, const float* __restrict__ cw, const float* __restrict__ cb,
    const float* __restrict__ Dskip, u16* __restrict__ y){
  __shared__ float ce[1024];
  int bx = blockIdx.x; int c = bx&31, h=(bx>>5)&7, b=bx>>8;
  int tid = threadIdx.x;
  size_t t0 = (size_t)b*Tn + c*64;
  int j = tid>>2, n0=(tid&3)*4;
  {
    ushort4v cv = *(const ushort4v*)(proj + (t0+j)*TOT2 + OFFC + h*16 + n0);
    float4 evv = *(const float4*)(expS + (t0+j)*128 + h*16 + n0);
    ce[j*16+n0+0] = b2f(cv[0])*evv.x; ce[j*16+n0+1] = b2f(cv[1])*evv.y;
    ce[j*16+n0+2] = b2f(cv[2])*evv.z; ce[j*16+n0+3] = b2f(cv[3])*evv.w;
  }
  __syncthreads();
  float h0[16];
  size_t base = ((((size_t)b*8+h)*NCH + c)*Px + tid)*16;
  #pragma unroll
  for (int n=0;n<16;n++) h0[n] = H0[base+n];
  int ch = h*Px + tid;
  float dsk = Dskip[ch];
  const u16* pxin = proj + t0*TOT2 + ch;
  float w0=cw[ch*4+0], w1=cw[ch*4+1], w2=cw[ch*4+2], w3=cw[ch*4+3];
  float bcv = cb[ch];
  float x3=0.f, x2=0.f, x1=0.f;
  if (c > 0){
    x3 = b2f(pxin[-(ptrdiff_t)3*TOT2]);
    x2 = b2f(pxin[-(ptrdiff_t)2*TOT2]);
    x1 = b2f(pxin[-(ptrdiff_t)TOT2]);
  }
  u16* yp = y + t0*DIx + ch;
  for (int jj=0;jj<64;jj++){
    float x0 = b2f(pxin[(size_t)jj*TOT2]);
    float cv = bcv + x3*w0 + x2*w1 + x1*w2 + x0*w3;
    float x = cv / (1.0f + expf(-cv));
    x3=x2; x2=x1; x1=x0;
    float f = 0.f;
    #pragma unroll
    for (int n=0;n<16;n++) f += ce[jj*16+n]*h0[n];
    size_t yi = (size_t)jj*DIx;
    yp[yi] = f2b(b2f(yp[yi]) + f + dsk*x);
  }
}

// ---------------- gated rms (y bf16, z bf16, stride TOT2) ----------------
__global__ __launch_bounds__(256) void k_gatedrms(const u16* __restrict__ y, const u16* __restrict__ proj,
     const float* __restrict__ w, u16* __restrict__ yn){
  int row = blockIdx.x, tid = threadIdx.x;
  const u16* yr = y + (size_t)row*DIx;
  const u16* zr = proj + (size_t)row*TOT2 + DIx;
  float v[8]; float ss=0.f;
  #pragma unroll
  for (int i=0;i<8;i++){
    int cidx = tid + i*256;
    float z = b2f(zr[cidx]);
    float g = b2f(yr[cidx]) * (z / (1.0f + expf(-z)));
    v[i]=g; ss += g*g;
  }
  ss = block_sum256(ss);
  float sc = rsqrtf(ss*(1.0f/2048.0f) + 1e-6f);
  u16* d = yn + (size_t)row*DIx;
  #pragma unroll
  for (int i=0;i<8;i++){ int cidx=tid+i*256; d[cidx] = f2b(v[i]*sc*w[cidx]); }
}

// ---------------- h = x + sout; u2 = rms(h)*w (bf16) ----------------
__global__ __launch_bounds__(256) void k_addrms(const float* __restrict__ x, const float* __restrict__ sout,
     const float* __restrict__ w, float* __restrict__ hbuf, u16* __restrict__ u2){
  int row=blockIdx.x, tid=threadIdx.x;
  float v[4]; float ss=0.f;
  #pragma unroll
  for (int i=0;i<4;i++){
    int cidx = tid + i*256;
    size_t idx = (size_t)row*1024 + cidx;
    float hv = x[idx] + sout[idx];
    hbuf[idx]=hv; v[i]=hv; ss+=hv*hv;
  }
  ss = block_sum256(ss);
  float sc = rsqrtf(ss*(1.0f/1024.0f)+1e-6f);
  #pragma unroll
  for (int i=0;i<4;i++){ int cidx=tid+i*256; u2[(size_t)row*1024+cidx] = f2b(v[i]*sc*w[cidx]); }
}

// ---------------- MFMA sliding-window attention ----------------
#define QT 64
#define KSPAN 192
__device__ __forceinline__ u32 swz128a(int row, int b){  // tile stride 128B
  return (u32)((row*128 + b) ^ ((((row&7)^((row>>3)&7)))<<4));
}
__device__ __forceinline__ u32 swz384a(int row, int b){  // tile stride 384B
  return (u32)((row*384 + b) ^ ((((row&7)^((row>>3)&7)))<<4));
}

__global__ __launch_bounds__(256) void k_attn_mfma(const u16* __restrict__ qr, const u16* __restrict__ kr,
    const u16* __restrict__ vr, u16* __restrict__ ya){
  __shared__ u16 bufK[KSPAN*64];   // 24576 B ; later P[64][192]
  __shared__ u16 bufV[64*KSPAN];   // 24576 B
  int tid = threadIdx.x, lane = tid&63, wid = tid>>6;
  int fr = lane&15, fq = lane>>4;
  int blk = blockIdx.x;            // bh*32 + qt
  int qt = blk & 31, bh = blk >> 5;
  int t0 = qt*QT;
  size_t rowbase = (size_t)bh*Tn;
  char* cK = (char*)bufK;
  char* cV = (char*)bufV;

  #pragma unroll
  for (int it=0; it<6; ++it){
    int chunk = it*256 + tid;
    int row = chunk>>3, c8 = chunk&7;
    int sg = t0 - 128 + row;
    if (sg >= 0){
      short8 v = *(const short8*)(kr + (rowbase+sg)*64 + c8*8);
      *(short8*)(cK + swz128a(row, c8*16)) = v;
    }
  }
  #pragma unroll
  for (int it=0; it<6; ++it){
    int idx = it*256 + tid;          // 1536 items
    int s = idx>>3, c8 = idx&7, d0 = c8*8;
    int sg = t0 - 128 + s;
    short8 v;
    if (sg >= 0) v = *(const short8*)(vr + (rowbase+sg)*64 + d0);
    else         v = short8{0,0,0,0,0,0,0,0};
    #pragma unroll
    for (int e=0;e<8;e++)
      *(u16*)(cV + swz384a(d0+e, s*2)) = (u16)v[e];
  }
  __syncthreads();

  f32x4 acc[12];
  #pragma unroll
  for (int j=0;j<12;j++)
    #pragma unroll
    for (int r=0;r<4;r++) acc[j][r]=0.f;
  #pragma unroll
  for (int kk=0;kk<2;kk++){
    short8 aq = *(const short8*)(qr + (rowbase + t0 + wid*16 + fr)*64 + kk*32 + fq*8);
    #pragma unroll
    for (int j=0;j<12;j++){
      short8 bk = *(const short8*)(cK + swz128a(j*16+fr, kk*64 + fq*16));
      acc[j] = __builtin_amdgcn_mfma_f32_16x16x32_bf16(aq, bk, acc[j], 0,0,0);
    }
  }

  float p[12][4];
  int cb = lane&15;
  #pragma unroll
  for (int r=0;r<4;r++){
    int rq = wid*16 + (lane>>4)*4 + r;
    float m = -3.0e38f;
    #pragma unroll
    for (int j=0;j<12;j++){
      int c = j*16 + cb;
      bool allowed = (c > rq) && (c <= rq+128) && (c >= 128 - t0);
      float v = allowed ? acc[j][r]*0.125f : -3.0e38f;
      p[j][r] = v;
      m = fmaxf(m, v);
    }
    #pragma unroll
    for (int o=1;o<16;o<<=1) m = fmaxf(m, __shfl_xor(m, o, 64));
    float sum = 0.f;
    #pragma unroll
    for (int j=0;j<12;j++){ float e = __expf(p[j][r]-m); p[j][r]=e; sum += e; }
    #pragma unroll
    for (int o=1;o<16;o<<=1) sum += __shfl_xor(sum, o, 64);
    float inv = 1.0f/sum;
    #pragma unroll
    for (int j=0;j<12;j++) p[j][r] *= inv;
  }
  __syncthreads();

  #pragma unroll
  for (int r=0;r<4;r++){
    int rq = wid*16 + (lane>>4)*4 + r;
    #pragma unroll
    for (int j=0;j<12;j++){
      *(u16*)(cK + swz384a(rq, (j*16+cb)*2)) = f2b(p[j][r]);
    }
  }
  __syncthreads();

  f32x4 acc2[4];
  #pragma unroll
  for (int f=0;f<4;f++)
    #pragma unroll
    for (int r=0;r<4;r++) acc2[f][r]=0.f;
  #pragma unroll
  for (int kk=0;kk<6;kk++){
    short8 ap = *(const short8*)(cK + swz384a(wid*16 + fr, kk*64 + fq*16));
    #pragma unroll
    for (int f=0;f<4;f++){
      short8 bv = *(const short8*)(cV + swz384a(f*16+fr, kk*64 + fq*16));
      acc2[f] = __builtin_amdgcn_mfma_f32_16x16x32_bf16(ap, bv, acc2[f], 0,0,0);
    }
  }
  int b = bh >> 4, h = bh & 15;
  #pragma unroll
  for (int f=0;f<4;f++){
    int d = f*16 + cb;
    #pragma unroll
    for (int r=0;r<4;r++){
      int q = t0 + wid*16 + (lane>>4)*4 + r;
      ya[((size_t)b*Tn + q)*Dm + h*64 + d] = f2b(acc2[f][r]);
    }
  }
}

// =================================================================
extern "C" void kernel_launch(void* const* d_in, const int* in_sizes, int n_in,
                              void* d_out, int out_size, void* d_ws, size_t ws_size,
                              hipStream_t stream) {
  const float* x        = (const float*)d_in[0];
  const float* norm1_w  = (const float*)d_in[1];
  const float* norm2_w  = (const float*)d_in[2];
  const float* Win      = (const float*)d_in[3];
  const float* Wdt      = (const float*)d_in[4];
  const float* conv_w   = (const float*)d_in[5];
  const float* conv_b   = (const float*)d_in[6];
  const float* A_log    = (const float*)d_in[7];
  const float* Dskip    = (const float*)d_in[8];
  const float* dt_bias  = (const float*)d_in[9];
  const float* ssd_norm = (const float*)d_in[10];
  const float* Wout_ssd = (const float*)d_in[11];
  const float* Wres     = (const float*)d_in[12];
  const float* Wq       = (const float*)d_in[13];
  const float* Wk       = (const float*)d_in[14];
  const float* Wv       = (const float*)d_in[15];
  const float* Wo       = (const float*)d_in[16];

  char* ws = (char*)d_ws;
  size_t off = 0;
  auto alloc = [&](size_t bytes){ size_t r = off; off += (bytes + 255) & ~(size_t)255; return r; };

  size_t o_WinB  = alloc((size_t)TOTx*Dm*2);      // contiguous with WresB: merged [6464,1024]
  size_t o_WresB = alloc((size_t)DIx*Dm*2);
  size_t o_WoutB = alloc((size_t)Dm*DIx*2);
  size_t o_WqB   = alloc((size_t)Dm*Dm*2);
  size_t o_WkB   = alloc((size_t)Dm*Dm*2);
  size_t o_WvB   = alloc((size_t)Dm*Dm*2);
  size_t o_WoB   = alloc((size_t)Dm*Dm*2);
  size_t o_u1    = alloc((size_t)BT*Dm*2);        // later reused as vr
  size_t o_proj  = alloc((size_t)BT*TOT2*2);      // merged bf16 proj (53MB)
  size_t o_sout  = alloc((size_t)BT*Dm*4);
  size_t o_dtA   = alloc((size_t)BT*H_SSM*Nst*4);
  size_t o_dtB   = alloc((size_t)BT*H_SSM*Nst*4);
  size_t o_expS  = alloc((size_t)BT*H_SSM*Nst*4);
  size_t o_LS    = alloc((size_t)Bsz*H_SSM*NCH*Px*Nst*4);
  size_t o_H0    = alloc((size_t)Bsz*H_SSM*NCH*Px*Nst*4);
  size_t o_y     = alloc((size_t)BT*DIx*2);       // ybuf16; later yatt
  size_t o_yn    = alloc((size_t)BT*DIx*2);       // yn; later u2
  size_t o_hb    = alloc((size_t)BT*Dm*4);
  size_t o_qr    = alloc((size_t)Bsz*H_ATTN*Tn*HDx*2);
  size_t o_kr    = alloc((size_t)Bsz*H_ATTN*Tn*HDx*2);

  u16* WinB  = (u16*)(ws + o_WinB);    // head of merged [Win;Wres] weight
  u16* WoutB = (u16*)(ws + o_WoutB);
  u16* WqB   = (u16*)(ws + o_WqB);
  u16* u1    = (u16*)(ws + o_u1);
  u16* projb = (u16*)(ws + o_proj);
  float* dtA  = (float*)(ws + o_dtA);
  float* dtB  = (float*)(ws + o_dtB);
  float* expS = (float*)(ws + o_expS);
  float* LS   = (float*)(ws + o_LS);
  float* H0   = (float*)(ws + o_H0);
  u16*   ybuf16 = (u16*)(ws + o_y);
  u16*   yn   = (u16*)(ws + o_yn);
  float* hb   = (float*)(ws + o_hb);
  float* sout = (float*)(ws + o_sout);
  // aliases (lifetimes disjoint)
  u16* qr = (u16*)(ws + o_qr);
  u16* kr = (u16*)(ws + o_kr);
  u16* vr = u1;                      // u1 dead after merged in-proj gemm
  u16* yatt = (u16*)(ws + o_y);      // ybuf16 dead after gatedrms

  // fused weight convert
  {
    CvtArgs a;
    a.s[0]=Win;  a.d[0]=WinB;  a.n[0]=TOTx*Dm;
    a.s[1]=Wres; a.d[1]=(u16*)(ws + o_WresB); a.n[1]=DIx*Dm;
    a.s[2]=Wout_ssd; a.d[2]=WoutB; a.n[2]=Dm*DIx;
    a.s[3]=Wq; a.d[3]=WqB; a.n[3]=Dm*Dm;
    a.s[4]=Wk; a.d[4]=(u16*)(ws + o_WkB); a.n[4]=Dm*Dm;
    a.s[5]=Wv; a.d[5]=(u16*)(ws + o_WvB); a.n[5]=Dm*Dm;
    a.s[6]=Wo; a.d[6]=(u16*)(ws + o_WoB); a.n[6]=Dm*Dm;
    int total4 = (a.n[0]+a.n[1]+a.n[2]+a.n[3]+a.n[4]+a.n[5]+a.n[6])/4;
    k_cvt_all<<<dim3((total4+255)/256), dim3(256), 0, stream>>>(a, total4);
  }

  // 1) u1 = rms(x, norm1_w)
  k_rms1024<<<dim3(BT), dim3(256), 0, stream>>>(x, norm1_w, u1);
  // 2) projb = bf16(u1 @ [Win;Wres]^T)  256^2 4-phase reg-cached: gxx=26, 416 blocks
  k_gemm256<<<dim3(16*26), dim3(512), 0, stream>>>(u1, WinB, projb, BT, TOT2, Dm, 26);
  // 3) dt prep
  k_dtprep<<<dim3(BT*H_SSM/256), dim3(256), 0, stream>>>(projb, Wdt, dt_bias, A_log, dtA, dtB);
  // 4) chunked scan (conv+silu fused; scan1 folds residual column; y bf16)
  k_scan1<<<dim3(Bsz*H_SSM*NCH), dim3(256), 0, stream>>>(dtA, dtB, projb, conv_w, conv_b, expS, ybuf16, LS);
  k_scan2<<<dim3(Bsz*H_SSM*16), dim3(256), 0, stream>>>(expS, LS, H0);
  k_scan3<<<dim3(Bsz*H_SSM*NCH), dim3(256), 0, stream>>>(projb, expS, H0, conv_w, conv_b, Dskip, ybuf16);
  // 5) yn = rms(y * silu(z)) * ssd_norm_w
  k_gatedrms<<<dim3(BT), dim3(256), 0, stream>>>(ybuf16, projb, ssd_norm, yn);
  // 6) sout = yn @ Wout^T  BN=64: gx=16, 512 blocks, K=2048
  k_gemm<1><<<dim3(16*32), dim3(256), 0, stream>>>(yn, WoutB, sout, nullptr, nullptr,
                                                   nullptr, nullptr, nullptr, BT, Dm, DIx, 16, 0);
  // 7) h = x + sout; u2 = rms(h)*norm2_w
  k_addrms<<<dim3(BT), dim3(256), 0, stream>>>(x, sout, norm2_w, hb, (u16*)(ws + o_yn));
  u16* u2p = (u16*)(ws + o_yn);
  // 8) fused QKV projection + RoPE + transpose (mode 5): gx=48, 1536 blocks
  k_gemm<1><<<dim3(48*32), dim3(256), 0, stream>>>(u2p, WqB, nullptr, nullptr, nullptr,
                                                   qr, kr, vr, BT, 3*Dm, Dm, 48, 5);
  // 9) attention (MFMA sliding-window)
  k_attn_mfma<<<dim3(Bsz*H_ATTN*(Tn/QT)), dim3(256), 0, stream>>>(qr, kr, vr, yatt);
  // 10) out = hb + yatt @ Wo^T  BN=64: gx=16, 512 blocks
  k_gemm<1><<<dim3(16*32), dim3(256), 0, stream>>>(yatt, (u16*)(ws + o_WoB), (float*)d_out, nullptr, hb,
                                                   nullptr, nullptr, nullptr, BT, Dm, Dm, 16, 3);
  (void)in_sizes; (void)n_in; (void)out_size; (void)ws_size;
}

// Round 16
// 268.451 us; speedup vs baseline: 1.2701x; 1.1956x over previous
//
#include <hip/hip_runtime.h>
#include <stdint.h>

typedef unsigned short u16;
typedef unsigned int u32;
typedef __attribute__((ext_vector_type(8))) short short8;
typedef __attribute__((ext_vector_type(4))) unsigned short ushort4v;
typedef __attribute__((ext_vector_type(4))) float f32x4;

// ---------------- problem constants ----------------
#define Bsz 2
#define Tn 2048
#define Dm 1024
#define H_ATTN 16
#define HDx 64
#define WINx 128
#define H_SSM 8
#define DIx 2048
#define Nst 16
#define DTRx 64
#define Px 256          // DI / H_SSM
#define TOTx 4416       // 2*DI + DTR + 2*H*N  (Win rows)
#define TOT2 6464       // TOTx + DIx : merged [Win;Wres] output width
#define RESOFF 4416     // residual (Wres) column offset in merged proj row
#define OFFC (2*DIx+DTRx+H_SSM*Nst)   // C-section offset in proj row
#define BT (Bsz*Tn)     // 4096
#define NCH 32          // chunks
#define LCH 64          // chunk length

// ---------------- helpers ----------------
__device__ __forceinline__ float b2f(u16 u){ u32 x = ((u32)u)<<16; float f; __builtin_memcpy(&f,&x,4); return f; }
__device__ __forceinline__ u16 f2b(float f){ u32 x; __builtin_memcpy(&x,&f,4); u32 r = x + 0x7fffu + ((x>>16)&1u); return (u16)(r>>16); }

__device__ __forceinline__ float block_sum256(float v){
  #pragma unroll
  for (int o=32;o;o>>=1) v += __shfl_xor(v,o,64);
  __shared__ float sb[4];
  int wid = threadIdx.x>>6;
  if ((threadIdx.x&63)==0) sb[wid]=v;
  __syncthreads();
  v = sb[0]+sb[1]+sb[2]+sb[3];
  __syncthreads();
  return v;
}

__device__ __forceinline__ void gload_lds16(const void* g, void* l){
  __builtin_amdgcn_global_load_lds((const __attribute__((address_space(1))) void*)g,
                                   (__attribute__((address_space(3))) void*)l, 16, 0, 0);
}

// ---------------- fused fp32 -> bf16 convert (all 7 weights, 1 launch) ----------------
struct CvtArgs { const float* s[7]; u16* d[7]; int n[7]; };
__global__ __launch_bounds__(256) void k_cvt_all(CvtArgs a, int total4){
  int i = blockIdx.x*256 + threadIdx.x;   // in float4 units
  if (i >= total4) return;
  int e = i*4;
  #pragma unroll
  for (int j=0;j<7;j++){
    if (e < a.n[j]){
      float4 v = *(const float4*)(a.s[j]+e);
      u16* d = a.d[j]+e;
      d[0]=f2b(v.x); d[1]=f2b(v.y); d[2]=f2b(v.z); d[3]=f2b(v.w);
      return;
    }
    e -= a.n[j];
  }
}

// ---------------- rms over 1024 (fp32 in -> bf16 out) ----------------
__global__ __launch_bounds__(256) void k_rms1024(const float* __restrict__ src, const float* __restrict__ w,
                                                 u16* __restrict__ dst){
  int row = blockIdx.x, tid = threadIdx.x;
  const float* s = src + (size_t)row*1024;
  float v[4]; float ss=0.f;
  #pragma unroll
  for (int i=0;i<4;i++){ v[i] = s[tid + i*256]; ss += v[i]*v[i]; }
  ss = block_sum256(ss);
  float sc = rsqrtf(ss*(1.0f/1024.0f) + 1e-6f);
  u16* d = dst + (size_t)row*1024;
  #pragma unroll
  for (int i=0;i<4;i++){ int c = tid+i*256; d[c] = f2b(v[i]*sc*w[c]); }
}

#define BKq 64

// ---------------- GEMM 256x256, BK=64, 8-wave 4-phase/K-tile (r13-best: reg-cached) ----
__global__ __launch_bounds__(512,1)
void k_gemm256(const u16* __restrict__ A, const u16* __restrict__ W,
               u16* __restrict__ C16, int M, int N, int K, int gxx){
  __shared__ u16 lds[2][4][128*64];
  int tid = threadIdx.x, lane = tid&63, wid = tid>>6;
  int bid = blockIdx.x;
  int xcd = bid&7, r = bid>>3;          // r in [0, 2*gxx)
  int halfg = gxx>>1;
  int row0 = (xcd>>1)<<2, col0 = (xcd&1)*halfg;
  int bx = col0 + (r>>2), by = row0 + (r&3);
  int bm = by*256, bn = bx*256;
  int wr = wid>>2, wcn = wid&3;          // wr in {0,1}, wcn in {0..3}
  int fr = lane&15, fq = lane>>4;
  f32x4 acc[2][2][4][2];
  #pragma unroll
  for (int a=0;a<2;a++)
    #pragma unroll
    for (int b=0;b<2;b++)
      #pragma unroll
      for (int c=0;c<4;c++)
        #pragma unroll
        for (int d=0;d<2;d++)
          #pragma unroll
          for (int rr=0;rr<4;rr++) acc[a][b][c][d][rr]=0.f;

  auto stageHalf = [&](int b, int q, int tt){
    int k0 = tt*BKq;
    #pragma unroll
    for (int i=0;i<2;i++){
      int idx = i*512 + tid;             // 0..1023 16B-chunks of this half
      int row = idx>>3, c8 = idx&7;
      const u16* src; int gr;
      if (q < 2){ gr = bm + q*128 + row;     if (gr > M-1) gr = M-1; src = A; }
      else      { gr = bn + (q-2)*128 + row; if (gr > N-1) gr = N-1; src = W; }
      gload_lds16(src + (size_t)gr*K + k0 + ((c8 ^ (row&7)))*8, &lds[b][q][(size_t)idx*8]);
    }
  };
  auto loadA = [&](const u16* aP, short8 (&af)[2][4]){
    #pragma unroll
    for (int kk=0;kk<2;kk++)
      #pragma unroll
      for (int mi=0;mi<4;mi++){
        int row = wr*64 + mi*16 + fr;
        af[kk][mi] = *(const short8*)(aP + row*64 + ((kk*4+fq) ^ (row&7))*8);
      }
  };
  auto loadB = [&](const u16* bP, short8 (&bf)[2][2]){
    #pragma unroll
    for (int kk=0;kk<2;kk++)
      #pragma unroll
      for (int ni=0;ni<2;ni++){
        int row = wcn*32 + ni*16 + fr;
        bf[kk][ni] = *(const short8*)(bP + row*64 + ((kk*4+fq) ^ (row&7))*8);
      }
  };

  int NT = K/BKq;
  stageHalf(0,0,0); stageHalf(0,2,0); stageHalf(0,3,0); stageHalf(0,1,0);

  short8 af[2][4], bf0[2][2], bf1[2][2];
  for (int t=0;t<NT;t++){
    int cb = t&1, nb = cb^1;
    int tn = (t+1 < NT) ? t+1 : t;       // clamped re-stage on last tile (unused)
    const u16* A0 = &lds[cb][0][0];
    const u16* A1 = &lds[cb][1][0];
    const u16* B0 = &lds[cb][2][0];
    const u16* B1 = &lds[cb][3][0];
    // ---- phase 0: compute (A0,B0); load af<-A0, bf0<-B0
    stageHalf(nb,0,tn);
    asm volatile("s_waitcnt vmcnt(6)" ::: "memory");
    __builtin_amdgcn_sched_barrier(0);
    __builtin_amdgcn_s_barrier();
    loadA(A0, af); loadB(B0, bf0);
    asm volatile("s_waitcnt lgkmcnt(0)" ::: "memory");
    __builtin_amdgcn_sched_barrier(0);
    __builtin_amdgcn_s_setprio(1);
    #pragma unroll
    for (int kk=0;kk<2;kk++)
      #pragma unroll
      for (int mi=0;mi<4;mi++)
        #pragma unroll
        for (int ni=0;ni<2;ni++)
          acc[0][0][mi][ni] = __builtin_amdgcn_mfma_f32_16x16x32_bf16(af[kk][mi], bf0[kk][ni], acc[0][0][mi][ni], 0,0,0);
    __builtin_amdgcn_s_setprio(0);
    __builtin_amdgcn_s_barrier();
    // ---- phase 1: compute (A0,B1); load bf1<-B1 (af reused)
    stageHalf(nb,2,tn);
    asm volatile("s_waitcnt vmcnt(6)" ::: "memory");
    __builtin_amdgcn_sched_barrier(0);
    __builtin_amdgcn_s_barrier();
    loadB(B1, bf1);
    asm volatile("s_waitcnt lgkmcnt(0)" ::: "memory");
    __builtin_amdgcn_sched_barrier(0);
    __builtin_amdgcn_s_setprio(1);
    #pragma unroll
    for (int kk=0;kk<2;kk++)
      #pragma unroll
      for (int mi=0;mi<4;mi++)
        #pragma unroll
        for (int ni=0;ni<2;ni++)
          acc[0][1][mi][ni] = __builtin_amdgcn_mfma_f32_16x16x32_bf16(af[kk][mi], bf1[kk][ni], acc[0][1][mi][ni], 0,0,0);
    __builtin_amdgcn_s_setprio(0);
    __builtin_amdgcn_s_barrier();
    // ---- phase 2: compute (A1,B1); load af<-A1 (bf1 reused)
    stageHalf(nb,3,tn);
    asm volatile("s_waitcnt vmcnt(6)" ::: "memory");
    __builtin_amdgcn_sched_barrier(0);
    __builtin_amdgcn_s_barrier();
    loadA(A1, af);
    asm volatile("s_waitcnt lgkmcnt(0)" ::: "memory");
    __builtin_amdgcn_sched_barrier(0);
    __builtin_amdgcn_s_setprio(1);
    #pragma unroll
    for (int kk=0;kk<2;kk++)
      #pragma unroll
      for (int mi=0;mi<4;mi++)
        #pragma unroll
        for (int ni=0;ni<2;ni++)
          acc[1][1][mi][ni] = __builtin_amdgcn_mfma_f32_16x16x32_bf16(af[kk][mi], bf1[kk][ni], acc[1][1][mi][ni], 0,0,0);
    __builtin_amdgcn_s_setprio(0);
    __builtin_amdgcn_s_barrier();
    // ---- phase 3: compute (A1,B0); pure register phase (af, bf0 reused)
    stageHalf(nb,1,tn);
    asm volatile("s_waitcnt vmcnt(6)" ::: "memory");
    __builtin_amdgcn_sched_barrier(0);
    __builtin_amdgcn_s_barrier();
    __builtin_amdgcn_s_setprio(1);
    #pragma unroll
    for (int kk=0;kk<2;kk++)
      #pragma unroll
      for (int mi=0;mi<4;mi++)
        #pragma unroll
        for (int ni=0;ni<2;ni++)
          acc[1][0][mi][ni] = __builtin_amdgcn_mfma_f32_16x16x32_bf16(af[kk][mi], bf0[kk][ni], acc[1][0][mi][ni], 0,0,0);
    __builtin_amdgcn_s_setprio(0);
    __builtin_amdgcn_s_barrier();
  }
  // epilogue: bf16 C write
  #pragma unroll
  for (int mh=0;mh<2;mh++)
    #pragma unroll
    for (int nh=0;nh<2;nh++)
      #pragma unroll
      for (int mi=0;mi<4;mi++)
        #pragma unroll
        for (int ni=0;ni<2;ni++){
          int row0o = bm + mh*128 + wr*64 + mi*16 + fq*4;
          int col  = bn + nh*128 + wcn*32 + ni*16 + fr;
          if (col < N){
            #pragma unroll
            for (int rr=0;rr<4;rr++)
              C16[(size_t)(row0o+rr)*N + col] = f2b(acc[mh][nh][mi][ni][rr]);
          }
        }
}

// ---------------- GEMM 128xBN, BK=64, depth-2 counted-vmcnt pipeline (r5-proven) ----
// NWC=1: BN=64, 48KB LDS, 3 blk/CU. XCD super-tiling.
// mode: 0 C=acc | 2 C16=bf16(acc) | 3 C=b2f(ADD16)+acc | 5 fused-QKV+RoPE transposed write
template<int NWC>
__global__ __launch_bounds__(256, (NWC==2?2:3))
void k_gemm(const u16* __restrict__ A, const u16* __restrict__ W,
            float* __restrict__ C, u16* __restrict__ C16, const u16* __restrict__ ADD16,
            u16* __restrict__ qro, u16* __restrict__ kro, u16* __restrict__ vro,
            int M, int N, int K, int gx, int mode){
  constexpr int BN    = 64*NWC;
  constexpr int ROWS  = 128 + BN;
  constexpr int NLOADS= ROWS/32;
  constexpr int MFRAG = (NWC==2)?4:2;
  __shared__ u16 lds[2][ROWS*64];
  int tid = threadIdx.x, lane = tid&63, wid = tid>>6;
  int nwg = gridDim.x;
  int cpx = nwg>>3;
  int bid = blockIdx.x;
  int swz = (bid&7)*cpx + (bid>>3);
  int fourgx = gx<<2;
  int super = swz / fourgx;
  int r     = swz % fourgx;
  int bx = r >> 2;
  int by = (super<<2) + (r&3);
  int bm = by*128, bn = bx*BN;
  int wc = (NWC==2) ? (wid&1) : 0;
  int wr = (NWC==2) ? (wid>>1) : wid;
  int fr = lane&15, fq = lane>>4;
  int s7 = fr&7;
  f32x4 acc[MFRAG][4];
  #pragma unroll
  for (int mi=0;mi<MFRAG;mi++)
    #pragma unroll
    for (int ni=0;ni<4;ni++)
      #pragma unroll
      for (int rr=0;rr<4;rr++) acc[mi][ni][rr]=0.f;

  auto stage = [&](int buf, int t){
    int k0 = t*BKq;
    #pragma unroll
    for (int i=0;i<NLOADS;i++){
      int chunk = i*256 + tid;
      int row = chunk>>3, c8 = chunk&7;
      const u16* src;
      if (row < 128){ int ra = bm + row; if (ra > M-1) ra = M-1; src = A + (size_t)ra*K; }
      else          { int rb = bn + row-128; if (rb > N-1) rb = N-1; src = W + (size_t)rb*K; }
      gload_lds16(src + k0 + ((c8 ^ (row&7)))*8, &lds[buf][(size_t)chunk*8]);
    }
  };

  int NT = K/BKq;
  stage(0, 0);
  stage(1, 1);
  for (int t=0;t<NT;t++){
    int cur = t&1;
    if (t+1 < NT){
      if constexpr (NWC==2) asm volatile("s_waitcnt vmcnt(8)" ::: "memory");
      else                  asm volatile("s_waitcnt vmcnt(6)" ::: "memory");
    } else {
      asm volatile("s_waitcnt vmcnt(0)" ::: "memory");
    }
    __builtin_amdgcn_sched_barrier(0);
    __builtin_amdgcn_s_barrier();
    #pragma unroll
    for (int kk=0;kk<2;kk++){
      short8 bf4[4], af4[MFRAG];
      int slotb = ((kk*4 + fq) ^ s7)*8;
      #pragma unroll
      for (int ni=0;ni<4;ni++)
        bf4[ni] = *(const short8*)(&lds[cur][(128 + wc*64 + ni*16 + fr)*64 + slotb]);
      #pragma unroll
      for (int mi=0;mi<MFRAG;mi++)
        af4[mi] = *(const short8*)(&lds[cur][(wr*(MFRAG*16) + mi*16 + fr)*64 + slotb]);
      #pragma unroll
      for (int mi=0;mi<MFRAG;mi++)
        #pragma unroll
        for (int ni=0;ni<4;ni++)
          acc[mi][ni] = __builtin_amdgcn_mfma_f32_16x16x32_bf16(af4[mi], bf4[ni], acc[mi][ni], 0,0,0);
    }
    asm volatile("s_waitcnt lgkmcnt(0)" ::: "memory");
    __builtin_amdgcn_sched_barrier(0);
    __builtin_amdgcn_s_barrier();
    if (t+2 < NT) stage(cur, t+2);
  }
  if (mode == 5){
    // fused QKV + RoPE epilogue: each 64-col tile = one head of one section.
    int sec = bn >> 10;                  // 0=Q, 1=K, 2=V
    int hh  = (bn >> 6) & 15;
    #pragma unroll
    for (int mi=0;mi<MFRAG;mi++){
      #pragma unroll
      for (int rr=0;rr<4;rr++){
        int row = bm + wr*(MFRAG*16) + mi*16 + fq*4 + rr;
        int tt = row & (Tn-1), bb = row >> 11;
        size_t dstb = (((size_t)bb*H_ATTN + hh)*Tn + tt)*64;
        if (sec == 2){
          #pragma unroll
          for (int ni=0;ni<4;ni++)
            vro[dstb + ni*16 + fr] = f2b(acc[mi][ni][rr]);
        } else {
          u16* dst = (sec==0) ? qro : kro;
          #pragma unroll
          for (int ni=0;ni<2;ni++){
            int dh = ni*16 + fr;
            float ang = (float)tt * exp2f(-(float)dh * (13.287712379549449f/32.0f));
            float cs = cosf(ang), sn = sinf(ang);
            float lo = acc[mi][ni][rr], hi = acc[mi][ni+2][rr];
            dst[dstb + dh]      = f2b(lo*cs - hi*sn);
            dst[dstb + dh + 32] = f2b(hi*cs + lo*sn);
          }
        }
      }
    }
    return;
  }
  #pragma unroll
  for (int mi=0;mi<MFRAG;mi++){
    int row0 = bm + wr*(MFRAG*16) + mi*16 + fq*4;
    #pragma unroll
    for (int ni=0;ni<4;ni++){
      int col = bn + wc*64 + ni*16 + fr;
      if (col < N){
        #pragma unroll
        for (int rr=0;rr<4;rr++){
          size_t idx = (size_t)(row0+rr)*N + col;
          float v = acc[mi][ni][rr];
          if (mode == 0)      C[idx] = v;
          else if (mode == 2) C16[idx] = f2b(v);
          else                C[idx] = b2f(ADD16[idx]) + v;
        }
      }
    }
  }
}

// ---------------- scan phase 1: local scan (dtprep + conv+silu + Dskip + residual fused) ----------------
__global__ __launch_bounds__(256) void k_scan1(
    const u16* __restrict__ proj, const float* __restrict__ Wdt,
    const float* __restrict__ dt_bias, const float* __restrict__ A_log,
    const float* __restrict__ cw, const float* __restrict__ cb,
    const float* __restrict__ Dskip,
    float* __restrict__ expS, u16* __restrict__ y, float* __restrict__ LS){
  __shared__ float sA[1024], sS[1024], sB[1024], sC[1024];
  int bx = blockIdx.x;                 // b*256 + h*32 + c
  int c = bx & 31, h = (bx>>5)&7, b = bx>>8;
  int tid = threadIdx.x;
  size_t t0 = (size_t)b*Tn + c*64;
  int j = tid>>2, q = tid&3, n0 = q*4;
  // ---- dt: 64-dot per row, 4 lanes/row x 16 MACs + 2 shuffles ----
  {
    const u16* dtl = proj + (t0+j)*TOT2 + 2*DIx + q*16;
    short8 d0 = *(const short8*)(dtl);
    short8 d1 = *(const short8*)(dtl+8);
    const float* wrow = Wdt + h*64 + q*16;
    float part = 0.f;
    #pragma unroll
    for (int e=0;e<8;e++){ part += b2f((u16)d0[e])*wrow[e]; part += b2f((u16)d1[e])*wrow[8+e]; }
    part += __shfl_xor(part, 1, 64);
    part += __shfl_xor(part, 2, 64);
    float v = part + dt_bias[h];
    float sp = (v > 20.0f) ? v : log1pf(expf(v));
    float dt = fminf(fmaxf(sp, 1e-4f), 1.0f);
    ushort4v bm4 = *(const ushort4v*)(proj + (t0+j)*TOT2 + 2*DIx + DTRx + h*16 + n0);
    ushort4v cm4 = *(const ushort4v*)(proj + (t0+j)*TOT2 + OFFC + h*16 + n0);
    #pragma unroll
    for (int i=0;i<4;i++){
      float Av = -expf(A_log[h*16 + n0 + i]);
      sA[j*16+n0+i] = dt*Av;
      sB[j*16+n0+i] = dt*b2f(bm4[i]);
      sC[j*16+n0+i] = b2f(cm4[i]);
    }
  }
  __syncthreads();
  if (tid < 16){
    float cum = 0.f;
    for (int jj=0;jj<64;jj++){ cum += sA[jj*16+tid]; sS[jj*16+tid] = cum; }
  }
  __syncthreads();
  {
    float e[4], s4[4];
    #pragma unroll
    for (int i=0;i<4;i++){ e[i] = expf(sA[j*16+n0+i]); s4[i] = expf(sS[j*16+n0+i]); }
    #pragma unroll
    for (int i=0;i<4;i++){ sA[j*16+n0+i] = e[i]; sS[j*16+n0+i] = s4[i]; }
    float4 ev; ev.x=s4[0]; ev.y=s4[1]; ev.z=s4[2]; ev.w=s4[3];
    *(float4*)(expS + (t0+j)*128 + h*16 + n0) = ev;
  }
  __syncthreads();
  float st[16];
  #pragma unroll
  for (int n=0;n<16;n++) st[n]=0.f;
  int ch = h*Px + tid;                        // xin channel
  const u16* pxin = proj + t0*TOT2 + ch;
  const u16* pres = proj + t0*TOT2 + RESOFF + ch;
  float w0=cw[ch*4+0], w1=cw[ch*4+1], w2=cw[ch*4+2], w3=cw[ch*4+3];
  float bcv = cb[ch];
  float dsk = Dskip[ch];
  float x3=0.f, x2=0.f, x1=0.f;
  if (c > 0){
    x3 = b2f(pxin[-(ptrdiff_t)3*TOT2]);
    x2 = b2f(pxin[-(ptrdiff_t)2*TOT2]);
    x1 = b2f(pxin[-(ptrdiff_t)TOT2]);
  }
  u16* yp = y + t0*DIx + ch;
  for (int jj=0;jj<64;jj++){
    float x0 = b2f(pxin[(size_t)jj*TOT2]);
    float cv = bcv + x3*w0 + x2*w1 + x1*w2 + x0*w3;
    float x = cv / (1.0f + expf(-cv));       // silu(conv)
    x3=x2; x2=x1; x1=x0;
    float acc = b2f(pres[(size_t)jj*TOT2]) + dsk*x;  // residual + Dskip*x folded here
    #pragma unroll
    for (int n=0;n<16;n++){ st[n] = st[n]*sA[jj*16+n] + x*sB[jj*16+n]; acc += st[n]*sC[jj*16+n]; }
    yp[(size_t)jj*DIx] = f2b(acc);
  }
  float* ls = LS + ((((size_t)b*8+h)*NCH + c)*Px + tid)*16;
  #pragma unroll
  for (int n=0;n<16;n++) ls[n] = st[n];
}

// ---------------- scan phase 2: chunk-state scan, parallel over (ch,n) ----------------
__global__ __launch_bounds__(256) void k_scan2(const float* __restrict__ expS, const float* __restrict__ LS,
                                               float* __restrict__ H0){
  int blk = blockIdx.x;
  int slice = blk & 15;              // 16-channel slice
  int bh = blk >> 4; int b = bh>>3, h = bh&7;
  int tid = threadIdx.x;
  int ch = slice*16 + (tid>>4);
  int n  = tid & 15;
  float Hs = 0.f;
  for (int c=0;c<NCH;c++){
    float dl = expS[((size_t)b*Tn + c*64 + 63)*128 + h*16 + n];
    size_t base = ((((size_t)b*8+h)*NCH + c)*Px + ch)*16 + n;
    H0[base] = Hs;
    Hs = Hs*dl + LS[base];
  }
}

// ---------------- scan phase 3: fixup only (conv-free), bf16 y RMW ----------------
__global__ __launch_bounds__(256) void k_scan3(const u16* __restrict__ proj, const float* __restrict__ expS,
    const float* __restrict__ H0, u16* __restrict__ y){
  __shared__ float ce[1024];
  int bx = blockIdx.x; int c = bx&31, h=(bx>>5)&7, b=bx>>8;
  int tid = threadIdx.x;
  size_t t0 = (size_t)b*Tn + c*64;
  int j = tid>>2, n0=(tid&3)*4;
  {
    ushort4v cv = *(const ushort4v*)(proj + (t0+j)*TOT2 + OFFC + h*16 + n0);
    float4 evv = *(const float4*)(expS + (t0+j)*128 + h*16 + n0);
    ce[j*16+n0+0] = b2f(cv[0])*evv.x; ce[j*16+n0+1] = b2f(cv[1])*evv.y;
    ce[j*16+n0+2] = b2f(cv[2])*evv.z; ce[j*16+n0+3] = b2f(cv[3])*evv.w;
  }
  __syncthreads();
  float h0[16];
  size_t base = ((((size_t)b*8+h)*NCH + c)*Px + tid)*16;
  #pragma unroll
  for (int n=0;n<16;n++) h0[n] = H0[base+n];
  int ch = h*Px + tid;
  u16* yp = y + t0*DIx + ch;
  for (int jj=0;jj<64;jj++){
    float f = 0.f;
    #pragma unroll
    for (int n=0;n<16;n++) f += ce[jj*16+n]*h0[n];
    size_t yi = (size_t)jj*DIx;
    yp[yi] = f2b(b2f(yp[yi]) + f);
  }
}

// ---------------- gated rms (y bf16, z bf16, stride TOT2) ----------------
__global__ __launch_bounds__(256) void k_gatedrms(const u16* __restrict__ y, const u16* __restrict__ proj,
     const float* __restrict__ w, u16* __restrict__ yn){
  int row = blockIdx.x, tid = threadIdx.x;
  const u16* yr = y + (size_t)row*DIx;
  const u16* zr = proj + (size_t)row*TOT2 + DIx;
  float v[8]; float ss=0.f;
  #pragma unroll
  for (int i=0;i<8;i++){
    int cidx = tid + i*256;
    float z = b2f(zr[cidx]);
    float g = b2f(yr[cidx]) * (z / (1.0f + expf(-z)));
    v[i]=g; ss += g*g;
  }
  ss = block_sum256(ss);
  float sc = rsqrtf(ss*(1.0f/2048.0f) + 1e-6f);
  u16* d = yn + (size_t)row*DIx;
  #pragma unroll
  for (int i=0;i<8;i++){ int cidx=tid+i*256; d[cidx] = f2b(v[i]*sc*w[cidx]); }
}

// ---------------- h = x + sout(bf16); hb bf16; u2 = rms(h)*w (bf16) ----------------
__global__ __launch_bounds__(256) void k_addrms(const float* __restrict__ x, const u16* __restrict__ sout16,
     const float* __restrict__ w, u16* __restrict__ hb16, u16* __restrict__ u2){
  int row=blockIdx.x, tid=threadIdx.x;
  float v[4]; float ss=0.f;
  #pragma unroll
  for (int i=0;i<4;i++){
    int cidx = tid + i*256;
    size_t idx = (size_t)row*1024 + cidx;
    float hv = x[idx] + b2f(sout16[idx]);
    hb16[idx] = f2b(hv);
    v[i]=hv; ss+=hv*hv;
  }
  ss = block_sum256(ss);
  float sc = rsqrtf(ss*(1.0f/1024.0f)+1e-6f);
  #pragma unroll
  for (int i=0;i<4;i++){ int cidx=tid+i*256; u2[(size_t)row*1024+cidx] = f2b(v[i]*sc*w[cidx]); }
}

// ---------------- MFMA sliding-window attention ----------------
#define QT 64
#define KSPAN 192
__device__ __forceinline__ u32 swz128a(int row, int b){  // tile stride 128B
  return (u32)((row*128 + b) ^ ((((row&7)^((row>>3)&7)))<<4));
}
__device__ __forceinline__ u32 swz384a(int row, int b){  // tile stride 384B
  return (u32)((row*384 + b) ^ ((((row&7)^((row>>3)&7)))<<4));
}

__global__ __launch_bounds__(256) void k_attn_mfma(const u16* __restrict__ qr, const u16* __restrict__ kr,
    const u16* __restrict__ vr, u16* __restrict__ ya){
  __shared__ u16 bufK[KSPAN*64];   // 24576 B ; later P[64][192]
  __shared__ u16 bufV[64*KSPAN];   // 24576 B
  int tid = threadIdx.x, lane = tid&63, wid = tid>>6;
  int fr = lane&15, fq = lane>>4;
  int blk = blockIdx.x;            // bh*32 + qt
  int qt = blk & 31, bh = blk >> 5;
  int t0 = qt*QT;
  size_t rowbase = (size_t)bh*Tn;
  char* cK = (char*)bufK;
  char* cV = (char*)bufV;

  #pragma unroll
  for (int it=0; it<6; ++it){
    int chunk = it*256 + tid;
    int row = chunk>>3, c8 = chunk&7;
    int sg = t0 - 128 + row;
    if (sg >= 0){
      short8 v = *(const short8*)(kr + (rowbase+sg)*64 + c8*8);
      *(short8*)(cK + swz128a(row, c8*16)) = v;
    }
  }
  #pragma unroll
  for (int it=0; it<6; ++it){
    int idx = it*256 + tid;          // 1536 items
    int s = idx>>3, c8 = idx&7, d0 = c8*8;
    int sg = t0 - 128 + s;
    short8 v;
    if (sg >= 0) v = *(const short8*)(vr + (rowbase+sg)*64 + d0);
    else         v = short8{0,0,0,0,0,0,0,0};
    #pragma unroll
    for (int e=0;e<8;e++)
      *(u16*)(cV + swz384a(d0+e, s*2)) = (u16)v[e];
  }
  __syncthreads();

  f32x4 acc[12];
  #pragma unroll
  for (int j=0;j<12;j++)
    #pragma unroll
    for (int r=0;r<4;r++) acc[j][r]=0.f;
  #pragma unroll
  for (int kk=0;kk<2;kk++){
    short8 aq = *(const short8*)(qr + (rowbase + t0 + wid*16 + fr)*64 + kk*32 + fq*8);
    #pragma unroll
    for (int j=0;j<12;j++){
      short8 bk = *(const short8*)(cK + swz128a(j*16+fr, kk*64 + fq*16));
      acc[j] = __builtin_amdgcn_mfma_f32_16x16x32_bf16(aq, bk, acc[j], 0,0,0);
    }
  }

  float p[12][4];
  int cb = lane&15;
  #pragma unroll
  for (int r=0;r<4;r++){
    int rq = wid*16 + (lane>>4)*4 + r;
    float m = -3.0e38f;
    #pragma unroll
    for (int j=0;j<12;j++){
      int c = j*16 + cb;
      bool allowed = (c > rq) && (c <= rq+128) && (c >= 128 - t0);
      float v = allowed ? acc[j][r]*0.125f : -3.0e38f;
      p[j][r] = v;
      m = fmaxf(m, v);
    }
    #pragma unroll
    for (int o=1;o<16;o<<=1) m = fmaxf(m, __shfl_xor(m, o, 64));
    float sum = 0.f;
    #pragma unroll
    for (int j=0;j<12;j++){ float e = __expf(p[j][r]-m); p[j][r]=e; sum += e; }
    #pragma unroll
    for (int o=1;o<16;o<<=1) sum += __shfl_xor(sum, o, 64);
    float inv = 1.0f/sum;
    #pragma unroll
    for (int j=0;j<12;j++) p[j][r] *= inv;
  }
  __syncthreads();

  #pragma unroll
  for (int r=0;r<4;r++){
    int rq = wid*16 + (lane>>4)*4 + r;
    #pragma unroll
    for (int j=0;j<12;j++){
      *(u16*)(cK + swz384a(rq, (j*16+cb)*2)) = f2b(p[j][r]);
    }
  }
  __syncthreads();

  f32x4 acc2[4];
  #pragma unroll
  for (int f=0;f<4;f++)
    #pragma unroll
    for (int r=0;r<4;r++) acc2[f][r]=0.f;
  #pragma unroll
  for (int kk=0;kk<6;kk++){
    short8 ap = *(const short8*)(cK + swz384a(wid*16 + fr, kk*64 + fq*16));
    #pragma unroll
    for (int f=0;f<4;f++){
      short8 bv = *(const short8*)(cV + swz384a(f*16+fr, kk*64 + fq*16));
      acc2[f] = __builtin_amdgcn_mfma_f32_16x16x32_bf16(ap, bv, acc2[f], 0,0,0);
    }
  }
  int b = bh >> 4, h = bh & 15;
  #pragma unroll
  for (int f=0;f<4;f++){
    int d = f*16 + cb;
    #pragma unroll
    for (int r=0;r<4;r++){
      int q = t0 + wid*16 + (lane>>4)*4 + r;
      ya[((size_t)b*Tn + q)*Dm + h*64 + d] = f2b(acc2[f][r]);
    }
  }
}

// =================================================================
extern "C" void kernel_launch(void* const* d_in, const int* in_sizes, int n_in,
                              void* d_out, int out_size, void* d_ws, size_t ws_size,
                              hipStream_t stream) {
  const float* x        = (const float*)d_in[0];
  const float* norm1_w  = (const float*)d_in[1];
  const float* norm2_w  = (const float*)d_in[2];
  const float* Win      = (const float*)d_in[3];
  const float* Wdt      = (const float*)d_in[4];
  const float* conv_w   = (const float*)d_in[5];
  const float* conv_b   = (const float*)d_in[6];
  const float* A_log    = (const float*)d_in[7];
  const float* Dskip    = (const float*)d_in[8];
  const float* dt_bias  = (const float*)d_in[9];
  const float* ssd_norm = (const float*)d_in[10];
  const float* Wout_ssd = (const float*)d_in[11];
  const float* Wres     = (const float*)d_in[12];
  const float* Wq       = (const float*)d_in[13];
  const float* Wk       = (const float*)d_in[14];
  const float* Wv       = (const float*)d_in[15];
  const float* Wo       = (const float*)d_in[16];

  char* ws = (char*)d_ws;
  size_t off = 0;
  auto alloc = [&](size_t bytes){ size_t r = off; off += (bytes + 255) & ~(size_t)255; return r; };

  size_t o_WinB  = alloc((size_t)TOTx*Dm*2);      // contiguous with WresB: merged [6464,1024]
  size_t o_WresB = alloc((size_t)DIx*Dm*2);
  size_t o_WoutB = alloc((size_t)Dm*DIx*2);
  size_t o_WqB   = alloc((size_t)Dm*Dm*2);
  size_t o_WkB   = alloc((size_t)Dm*Dm*2);
  size_t o_WvB   = alloc((size_t)Dm*Dm*2);
  size_t o_WoB   = alloc((size_t)Dm*Dm*2);
  size_t o_u1    = alloc((size_t)BT*Dm*2);        // later reused as vr
  size_t o_proj  = alloc((size_t)BT*TOT2*2);      // merged bf16 proj (53MB)
  size_t o_sout  = alloc((size_t)BT*Dm*2);        // bf16 now
  size_t o_expS  = alloc((size_t)BT*H_SSM*Nst*4);
  size_t o_LS    = alloc((size_t)Bsz*H_SSM*NCH*Px*Nst*4);
  size_t o_H0    = alloc((size_t)Bsz*H_SSM*NCH*Px*Nst*4);
  size_t o_y     = alloc((size_t)BT*DIx*2);       // ybuf16; later yatt
  size_t o_yn    = alloc((size_t)BT*DIx*2);       // yn; later u2
  size_t o_hb    = alloc((size_t)BT*Dm*2);        // bf16 now
  size_t o_qr    = alloc((size_t)Bsz*H_ATTN*Tn*HDx*2);
  size_t o_kr    = alloc((size_t)Bsz*H_ATTN*Tn*HDx*2);

  u16* WinB  = (u16*)(ws + o_WinB);    // head of merged [Win;Wres] weight
  u16* WoutB = (u16*)(ws + o_WoutB);
  u16* WqB   = (u16*)(ws + o_WqB);
  u16* u1    = (u16*)(ws + o_u1);
  u16* projb = (u16*)(ws + o_proj);
  float* expS = (float*)(ws + o_expS);
  float* LS   = (float*)(ws + o_LS);
  float* H0   = (float*)(ws + o_H0);
  u16*   ybuf16 = (u16*)(ws + o_y);
  u16*   yn   = (u16*)(ws + o_yn);
  u16*   hb16 = (u16*)(ws + o_hb);
  u16*   sout16 = (u16*)(ws + o_sout);
  // aliases (lifetimes disjoint)
  u16* qr = (u16*)(ws + o_qr);
  u16* kr = (u16*)(ws + o_kr);
  u16* vr = u1;                      // u1 dead after merged in-proj gemm
  u16* yatt = (u16*)(ws + o_y);      // ybuf16 dead after gatedrms

  // fused weight convert
  {
    CvtArgs a;
    a.s[0]=Win;  a.d[0]=WinB;  a.n[0]=TOTx*Dm;
    a.s[1]=Wres; a.d[1]=(u16*)(ws + o_WresB); a.n[1]=DIx*Dm;
    a.s[2]=Wout_ssd; a.d[2]=WoutB; a.n[2]=Dm*DIx;
    a.s[3]=Wq; a.d[3]=WqB; a.n[3]=Dm*Dm;
    a.s[4]=Wk; a.d[4]=(u16*)(ws + o_WkB); a.n[4]=Dm*Dm;
    a.s[5]=Wv; a.d[5]=(u16*)(ws + o_WvB); a.n[5]=Dm*Dm;
    a.s[6]=Wo; a.d[6]=(u16*)(ws + o_WoB); a.n[6]=Dm*Dm;
    int total4 = (a.n[0]+a.n[1]+a.n[2]+a.n[3]+a.n[4]+a.n[5]+a.n[6])/4;
    k_cvt_all<<<dim3((total4+255)/256), dim3(256), 0, stream>>>(a, total4);
  }

  // 1) u1 = rms(x, norm1_w)
  k_rms1024<<<dim3(BT), dim3(256), 0, stream>>>(x, norm1_w, u1);
  // 2) projb = bf16(u1 @ [Win;Wres]^T)  256^2 4-phase reg-cached: gxx=26, 416 blocks
  k_gemm256<<<dim3(16*26), dim3(512), 0, stream>>>(u1, WinB, projb, BT, TOT2, Dm, 26);
  // 3) chunked scan (dtprep + conv + silu + Dskip + residual fused into scan1)
  k_scan1<<<dim3(Bsz*H_SSM*NCH), dim3(256), 0, stream>>>(projb, Wdt, dt_bias, A_log,
                                                         conv_w, conv_b, Dskip, expS, ybuf16, LS);
  k_scan2<<<dim3(Bsz*H_SSM*16), dim3(256), 0, stream>>>(expS, LS, H0);
  k_scan3<<<dim3(Bsz*H_SSM*NCH), dim3(256), 0, stream>>>(projb, expS, H0, ybuf16);
  // 4) yn = rms(y * silu(z)) * ssd_norm_w
  k_gatedrms<<<dim3(BT), dim3(256), 0, stream>>>(ybuf16, projb, ssd_norm, yn);
  // 5) sout16 = bf16(yn @ Wout^T)  BN=64: gx=16, 512 blocks, K=2048
  k_gemm<1><<<dim3(16*32), dim3(256), 0, stream>>>(yn, WoutB, nullptr, sout16, nullptr,
                                                   nullptr, nullptr, nullptr, BT, Dm, DIx, 16, 2);
  // 6) h = x + sout; hb bf16; u2 = rms(h)*norm2_w
  k_addrms<<<dim3(BT), dim3(256), 0, stream>>>(x, sout16, norm2_w, hb16, (u16*)(ws + o_yn));
  u16* u2p = (u16*)(ws + o_yn);
  // 7) fused QKV projection + RoPE + transpose (mode 5): gx=48, 1536 blocks
  k_gemm<1><<<dim3(48*32), dim3(256), 0, stream>>>(u2p, WqB, nullptr, nullptr, nullptr,
                                                   qr, kr, vr, BT, 3*Dm, Dm, 48, 5);
  // 8) attention (MFMA sliding-window)
  k_attn_mfma<<<dim3(Bsz*H_ATTN*(Tn/QT)), dim3(256), 0, stream>>>(qr, kr, vr, yatt);
  // 9) out = b2f(hb16) + yatt @ Wo^T  BN=64: gx=16, 512 blocks
  k_gemm<1><<<dim3(16*32), dim3(256), 0, stream>>>(yatt, (u16*)(ws + o_WoB), (float*)d_out, nullptr, hb16,
                                                   nullptr, nullptr, nullptr, BT, Dm, Dm, 16, 3);
  (void)in_sizes; (void)n_in; (void)out_size; (void)ws_size;
}